// Round 2
// baseline (1438.145 us; speedup 1.0000x reference)
//
#include <hip/hip_runtime.h>
#include <stdint.h>
#include <stddef.h>

// ---------------------------------------------------------------------------
// CSTreeLSTM on gfx950. Levels 1,16,256,4096,65536 (x offsets 0,1,17,273,4369),
// IN=HID=512. Leaf level fused chunk-wise into level-3 accumulators so the
// workspace stays ~106 MB (round-1 failure: 592 MB ws overflow -> page fault).
// GEMM: fp32 A staged+converted to bf16 in-kernel; bf16 B via global_load_lds.
// ---------------------------------------------------------------------------

typedef __bf16 bf16x8 __attribute__((ext_vector_type(8)));
typedef float  f32x4  __attribute__((ext_vector_type(4)));
typedef void __attribute__((address_space(3))) lds_void_t;
typedef void __attribute__((address_space(1))) gbl_void_t;

__device__ __forceinline__ uint16_t f2bf(float f) {
  union { float f; uint32_t u; } v; v.f = f;
  return (uint16_t)((v.u + 0x7fffu + ((v.u >> 16) & 1u)) >> 16);
}
__device__ __forceinline__ float sigmoidf_(float x) {
  return 1.0f / (1.0f + __expf(-x));
}

// ---- fp32 -> bf16 convert (weights only) ----------------------------------
__global__ void k_conv_bf16_v4(const float4* __restrict__ src,
                               ushort4* __restrict__ dst, long n4) {
  long i = blockIdx.x * (long)blockDim.x + threadIdx.x;
  long stride = (long)gridDim.x * blockDim.x;
  for (; i < n4; i += stride) {
    float4 v = src[i];
    ushort4 r;
    r.x = f2bf(v.x); r.y = f2bf(v.y); r.z = f2bf(v.z); r.w = f2bf(v.w);
    dst[i] = r;
  }
}

// ---- GEMM: C[m,n] = sum_k A32[m,k] * B16[n,k] -----------------------------
// A fp32 (converted to bf16 during LDS staging), B bf16 row-major [N,K].
// 128x128 tile, BK=32, 256 threads = 4 waves in 2x2, each 64x64 via 4x4
// mfma_f32_16x16x32_bf16. N must be a multiple of 128; M arbitrary (clamped
// loads, masked stores).
#define BM 128
#define BN 128
#define BK 32

__global__ __launch_bounds__(256)
void k_gemm_a32_bt(const float* __restrict__ A, int lda,
                   const uint16_t* __restrict__ B, int ldb,
                   float* __restrict__ C, int ldc,
                   int M, int K) {
  __shared__ uint16_t As[BM * BK];   // 8 KB bf16 (converted A)
  __shared__ uint16_t Bs[BN * BK];   // 8 KB bf16

  const int tid  = threadIdx.x;
  const int lane = tid & 63;
  const int wave = tid >> 6;
  const int lrow = lane & 15;
  const int quad = lane >> 4;
  const int wm = (wave >> 1) * 64;
  const int wn = (wave & 1) * 64;
  const long tm = blockIdx.x;
  const long tn = blockIdx.y;

  f32x4 acc[4][4] = {};

  const int srow = lane >> 2;         // staging row within 16-row group
  const int scol = (lane & 3) * 8;    // element offset in K (8 elems = 16B bf16)

  for (int k0 = 0; k0 < K; k0 += BK) {
    // B: async global->LDS, bf16, wave-uniform base + lane*16B (m97 pattern)
#pragma unroll
    for (int i = 0; i < 2; ++i) {
      int row = i * 64 + wave * 16 + srow;
      long grow = tn * BN + row;                 // N multiple of 128: in-bounds
      const uint16_t* gp = B + grow * (long)ldb + k0 + scol;
      uint16_t* lp = &Bs[i * 2048 + wave * 512];
      __builtin_amdgcn_global_load_lds((gbl_void_t*)(uintptr_t)gp,
                                       (lds_void_t*)lp, 16, 0, 0);
    }
    // A: fp32 global -> regs -> cvt bf16 -> contiguous ds_write_b128
#pragma unroll
    for (int i = 0; i < 2; ++i) {
      int row = i * 64 + wave * 16 + srow;
      long grow = tm * BM + row;
      if (grow >= M) grow = M - 1;               // clamp; stores masked below
      const float4* ap = (const float4*)(A + grow * (long)lda + k0 + scol);
      float4 v0 = ap[0], v1 = ap[1];
      bf16x8 r;
      r[0] = (__bf16)v0.x; r[1] = (__bf16)v0.y;
      r[2] = (__bf16)v0.z; r[3] = (__bf16)v0.w;
      r[4] = (__bf16)v1.x; r[5] = (__bf16)v1.y;
      r[6] = (__bf16)v1.z; r[7] = (__bf16)v1.w;
      // wave region is contiguous: lane writes region_base + lane*16B
      *(bf16x8*)&As[(i * 64 + wave * 16) * BK + lane * 8] = r;
    }
    __syncthreads();   // compiler drains vmcnt+lgkmcnt before barrier

    bf16x8 a[4], b[4];
#pragma unroll
    for (int f = 0; f < 4; ++f)
      a[f] = *(const bf16x8*)&As[(wm + f * 16 + lrow) * BK + quad * 8];
#pragma unroll
    for (int f = 0; f < 4; ++f)
      b[f] = *(const bf16x8*)&Bs[(wn + f * 16 + lrow) * BK + quad * 8];
#pragma unroll
    for (int fm = 0; fm < 4; ++fm)
#pragma unroll
      for (int fn = 0; fn < 4; ++fn)
        acc[fm][fn] = __builtin_amdgcn_mfma_f32_16x16x32_bf16(
            a[fm], b[fn], acc[fm][fn], 0, 0, 0);
    __syncthreads();
  }

  // C/D layout: col = lane&15, row = quad*4 + reg  [HW-verified mapping]
#pragma unroll
  for (int fm = 0; fm < 4; ++fm) {
#pragma unroll
    for (int fn = 0; fn < 4; ++fn) {
      long col  = tn * BN + wn + fn * 16 + lrow;
      long row0 = tm * BM + wm + fm * 16 + quad * 4;
#pragma unroll
      for (int r = 0; r < 4; ++r) {
        long row = row0 + r;
        if (row < M) C[row * (long)ldc + col] = acc[fm][fn][r];
      }
    }
  }
}

// ---- leaf elementwise: C = sig(i)*tanh(u), H = sig(o)*tanh(C) --------------
__global__ void k_leaf_ew(const float* __restrict__ G,
                          const float* __restrict__ bi,
                          const float* __restrict__ bo,
                          const float* __restrict__ bu,
                          float* __restrict__ H, float* __restrict__ Cv,
                          long rows) {
  long idx = blockIdx.x * (long)blockDim.x + threadIdx.x;
  if (idx >= rows * 512) return;
  long r = idx >> 9; int h = idx & 511;
  const float* g = G + r * 1536;
  float i = sigmoidf_(g[h] + bi[h]);
  float o = sigmoidf_(g[512 + h] + bo[h]);
  float u = tanhf(g[1024 + h] + bu[h]);
  float c = i * u;
  H[r * 512 + h]  = o * tanhf(c);
  Cv[r * 512 + h] = c;
}

// ---- chunk h_sum: hsum3[pbase+pl] = sum_b H_ch[pl*16+b] --------------------
__global__ void k_hsum_chunk(const float* __restrict__ Hch,
                             float* __restrict__ hsum3, int pbase, int nPar) {
  long idx = blockIdx.x * (long)blockDim.x + threadIdx.x;
  if (idx >= (long)nPar * 512) return;
  long pl = idx >> 9; int h = idx & 511;
  const float* hp = Hch + (pl << 4) * 512 + h;
  float s = 0.f;
#pragma unroll
  for (int b = 0; b < 16; ++b) s += hp[b * 512];
  hsum3[(long)(pbase + pl) * 512 + h] = s;
}

// ---- pack xh for level 3 from x + precomputed hsum3 ------------------------
__global__ void k_pack_xh3(const float* __restrict__ x3,
                           const float* __restrict__ hsum,
                           float* __restrict__ xh, int n) {
  long idx = blockIdx.x * (long)blockDim.x + threadIdx.x;
  if (idx >= (long)n * 512) return;
  long p = idx >> 9; int h = idx & 511;
  xh[p * 1024 + h]       = x3[p * 512 + h];
  xh[p * 1024 + 512 + h] = hsum[p * 512 + h];
}

// ---- upper-level h_sum + pack xh (children H in fp32) ----------------------
__global__ void k_hsum_xh(const float* __restrict__ Hc,
                          const float* __restrict__ xd,
                          float* __restrict__ xh, int n) {
  long idx = blockIdx.x * (long)blockDim.x + threadIdx.x;
  if (idx >= (long)n * 512) return;
  long p = idx >> 9; int h = idx & 511;
  const float* hp = Hc + (p << 4) * 512 + h;
  float s = 0.f;
#pragma unroll
  for (int b = 0; b < 16; ++b) s += hp[b * 512];
  xh[p * 1024 + h]       = xd[p * 512 + h];
  xh[p * 1024 + 512 + h] = s;
}

// ---- forget combine: Fpart[pg] = sum_b sig(fx+fc+bf)*C_child ---------------
// Fc and Cc indexed chunk-locally (cl = pl*16+b); Fx/Fpart globally via pbase.
__global__ void k_combine(const float* __restrict__ Fc,
                          const float* __restrict__ Fx,
                          const float* __restrict__ bfb,
                          const float* __restrict__ Cc,
                          float* __restrict__ Fpart,
                          int parentBase, int nParents) {
  long idx = blockIdx.x * (long)blockDim.x + threadIdx.x;
  if (idx >= (long)nParents * 512) return;
  long pl = idx >> 9; int h = idx & 511;
  long pg = parentBase + pl;
  float fx = Fx[pg * 512 + h] + bfb[h];
  float acc = 0.f;
#pragma unroll
  for (int b = 0; b < 16; ++b) {
    long cl = pl * 16 + b;
    acc += sigmoidf_(fx + Fc[cl * 512 + h]) * Cc[cl * 512 + h];
  }
  Fpart[pg * 512 + h] = acc;
}

// ---- exact fp32 fc for tiny levels (d=0): Fc[c,h] = C[c]·wf_w[h,512:1024] --
__global__ void k_fc_exact(const float* __restrict__ Cc,
                           const float* __restrict__ wf_w,
                           float* __restrict__ Fc, int nch) {
  long idx = blockIdx.x * (long)blockDim.x + threadIdx.x;
  if (idx >= (long)nch * 512) return;
  long c = idx >> 9; int h = idx & 511;
  const float* cr = Cc + c * 512;
  const float* wr = wf_w + (long)h * 1024 + 512;
  float s = 0.f;
  for (int k = 0; k < 512; ++k) s += cr[k] * wr[k];
  Fc[c * 512 + h] = s;
}

// ---- internal final: C = i*u + Fpart, H = o*tanh(C) ------------------------
__global__ void k_final(const float* __restrict__ G,
                        const float* __restrict__ Fpart,
                        const float* __restrict__ bi,
                        const float* __restrict__ bo,
                        const float* __restrict__ bu,
                        float* __restrict__ H, float* __restrict__ Cv, int n) {
  long idx = blockIdx.x * (long)blockDim.x + threadIdx.x;
  if (idx >= (long)n * 512) return;
  long p = idx >> 9; int h = idx & 511;
  const float* g = G + p * 1536;
  float i = sigmoidf_(g[h] + bi[h]);
  float o = sigmoidf_(g[512 + h] + bo[h]);
  float u = tanhf(g[1024 + h] + bu[h]);
  float c = i * u + Fpart[p * 512 + h];
  H[p * 512 + h]  = o * tanhf(c);
  Cv[p * 512 + h] = c;
}

// ---------------------------------------------------------------------------
extern "C" void kernel_launch(void* const* d_in, const int* in_sizes, int n_in,
                              void* d_out, int out_size, void* d_ws, size_t ws_size,
                              hipStream_t stream) {
  const float* x    = (const float*)d_in[0];
  const float* wi_w = (const float*)d_in[1];
  const float* wi_b = (const float*)d_in[2];
  const float* wf_w = (const float*)d_in[3];
  const float* wf_b = (const float*)d_in[4];
  const float* wo_w = (const float*)d_in[5];
  const float* wo_b = (const float*)d_in[6];
  const float* wu_w = (const float*)d_in[7];
  const float* wu_b = (const float*)d_in[8];
  (void)in_sizes; (void)n_in; (void)out_size; (void)ws_size;

  static const int  sizes[5] = {1, 16, 256, 4096, 65536};
  static const long offs[5]  = {0, 1, 17, 273, 4369};
  const int CHUNK = 4096;           // leaf rows per chunk (16 chunks)
  const int PCH   = CHUNK / 16;     // parents per chunk (256)

  // ---- workspace layout, ~106 MB total ----
  char* ws = (char*)d_ws;
  size_t off = 0;
  auto alloc = [&](size_t bytes) -> void* {
    void* p = ws + off;
    off += (bytes + 255) & ~(size_t)255;
    return p;
  };
  uint16_t* Wg    = (uint16_t*)alloc((size_t)1536 * 1024 * 2);  // 3.1 MB (i,o,u)
  uint16_t* Wf    = (uint16_t*)alloc((size_t)512 * 1024 * 2);   // 1.0 MB
  float*    G     = (float*)alloc((size_t)4096 * 1536 * 4);     // 25.2 MB
  float*    xh    = (float*)alloc((size_t)4096 * 1024 * 4);     // 16.8 MB
  float*    Hch   = (float*)alloc((size_t)CHUNK * 512 * 4);     // 8.4 MB
  float*    Cch   = (float*)alloc((size_t)CHUNK * 512 * 4);     // 8.4 MB
  float*    hsum3 = (float*)alloc((size_t)4096 * 512 * 4);      // 8.4 MB
  float*    Fx    = (float*)alloc((size_t)4096 * 512 * 4);      // 8.4 MB
  float*    Fpart = (float*)alloc((size_t)4096 * 512 * 4);      // 8.4 MB
  float*    Fc    = (float*)alloc((size_t)4096 * 512 * 4);      // 8.4 MB
  float*    HupA  = (float*)alloc((size_t)4096 * 512 * 4);      // 8.4 MB
  float*    CupA  = (float*)alloc((size_t)4096 * 512 * 4);      // 8.4 MB
  float*    HupB  = (float*)alloc((size_t)256 * 512 * 4);       // 0.5 MB
  float*    CupB  = (float*)alloc((size_t)256 * 512 * 4);       // 0.5 MB

  auto conv = [&](const float* s, uint16_t* d, long n) {
    long n4 = n >> 2;
    int grid = (int)((n4 + 255) / 256);
    if (grid > 4096) grid = 4096;
    k_conv_bf16_v4<<<grid, 256, 0, stream>>>((const float4*)s, (ushort4*)d, n4);
  };
  conv(wi_w, Wg,                (long)512 * 1024);
  conv(wo_w, Wg + 512 * 1024,   (long)512 * 1024);
  conv(wu_w, Wg + 1024 * 1024,  (long)512 * 1024);
  conv(wf_w, Wf,                (long)512 * 1024);

  auto gemm = [&](const float* A, int lda, const uint16_t* B, int ldb,
                  float* Cp, int ldc, int M, int N, int K) {
    dim3 grid((M + BM - 1) / BM, N / BN);
    k_gemm_a32_bt<<<grid, 256, 0, stream>>>(A, lda, B, ldb, Cp, ldc, M, K);
  };
  auto blks = [](long n) { return (int)((n + 255) / 256); };

  const float* x3 = x + offs[3] * 512;

  // Fx for level 3 (parents of leaves), once
  gemm(x3, 512, Wf, 1024, Fx, 512, 4096, 512, 512);

  // ---- leaf level fused chunk-wise into level-3 accumulators ----
  for (int c = 0; c < 65536 / CHUNK; ++c) {
    long base  = (long)c * CHUNK;
    int  pbase = c * PCH;
    // gates: [CHUNK,512] x Wg[:, :512]^T (h=0 at leaves => K=512)
    gemm(x + (offs[4] + base) * 512, 512, Wg, 1024, G, 1536, CHUNK, 1536, 512);
    k_leaf_ew<<<blks((long)CHUNK * 512), 256, 0, stream>>>(
        G, wi_b, wo_b, wu_b, Hch, Cch, CHUNK);
    k_hsum_chunk<<<blks((long)PCH * 512), 256, 0, stream>>>(
        Hch, hsum3, pbase, PCH);
    // fc for this chunk's children: [CHUNK,512] x Wf[:, 512:]^T
    gemm(Cch, 512, Wf + 512, 1024, Fc, 512, CHUNK, 512, 512);
    k_combine<<<blks((long)PCH * 512), 256, 0, stream>>>(
        Fc, Fx, wf_b, Cch, Fpart, pbase, PCH);
  }

  // ---- level 3 finalize ----
  k_pack_xh3<<<blks((long)4096 * 512), 256, 0, stream>>>(x3, hsum3, xh, 4096);
  gemm(xh, 1024, Wg, 1024, G, 1536, 4096, 1536, 1024);
  k_final<<<blks((long)4096 * 512), 256, 0, stream>>>(
      G, Fpart, wi_b, wo_b, wu_b, HupA, CupA, 4096);

  // ---- levels 2,1,0 ----
  float* Hcs[3] = {HupA, HupB, HupA};   // children H for d=2,1,0
  float* Ccs[3] = {CupA, CupB, CupA};
  float* Hos[3] = {HupB, HupA, (float*)d_out};
  float* Cos[3] = {CupB, CupA, (float*)d_out + 512};
  for (int j = 0; j < 3; ++j) {
    int d   = 2 - j;
    int n   = sizes[d];
    int nch = sizes[d + 1];
    const float* xd = x + offs[d] * 512;

    k_hsum_xh<<<blks((long)n * 512), 256, 0, stream>>>(Hcs[j], xd, xh, n);
    gemm(xh, 1024, Wg, 1024, G, 1536, n, 1536, 1024);
    gemm(xd, 512, Wf, 1024, Fx, 512, n, 512, 512);
    if (d >= 1) {
      gemm(Ccs[j], 512, Wf + 512, 1024, Fc, 512, nch, 512, 512);
    } else {
      k_fc_exact<<<blks((long)nch * 512), 256, 0, stream>>>(
          Ccs[j], wf_w, Fc, nch);
    }
    k_combine<<<blks((long)n * 512), 256, 0, stream>>>(
        Fc, Fx, wf_b, Ccs[j], Fpart, 0, n);
    k_final<<<blks((long)n * 512), 256, 0, stream>>>(
        G, Fpart, wi_b, wo_b, wu_b, Hos[j], Cos[j], n);
  }
}

// Round 3
// 847.649 us; speedup vs baseline: 1.6966x; 1.6966x over previous
//
#include <hip/hip_runtime.h>
#include <stdint.h>
#include <stddef.h>

// ---------------------------------------------------------------------------
// CSTreeLSTM on gfx950. Levels 1,16,256,4096,65536 (x offsets 0,1,17,273,4369),
// IN=HID=512. Round 3: CHUNK=16384 (4 leaf chunks), fused leaf ew+hsum (no H
// materialization, bf16 gate preacts), wave-dot kernels for starved GEMMs.
// Workspace ~164 MB (ws_size ~572 MB).
// ---------------------------------------------------------------------------

typedef __bf16 bf16x8 __attribute__((ext_vector_type(8)));
typedef __bf16 bf16x4 __attribute__((ext_vector_type(4)));
typedef float  f32x4  __attribute__((ext_vector_type(4)));
typedef void __attribute__((address_space(3))) lds_void_t;
typedef void __attribute__((address_space(1))) gbl_void_t;

__device__ __forceinline__ uint16_t f2bf(float f) {
  union { float f; uint32_t u; } v; v.f = f;
  return (uint16_t)((v.u + 0x7fffu + ((v.u >> 16) & 1u)) >> 16);
}
__device__ __forceinline__ float bf2f(uint16_t u) {
  union { uint32_t u; float f; } v; v.u = (uint32_t)u << 16;
  return v.f;
}
__device__ __forceinline__ float sig_(float x) {
  return 1.0f / (1.0f + __expf(-x));    // x=-inf -> 1/inf = 0, no NaN
}
__device__ __forceinline__ float tanh_(float x) {
  x = fminf(15.f, fmaxf(-15.f, x));     // clamp so e^{2x} can't overflow
  float e = __expf(2.f * x);
  return (e - 1.f) / (e + 1.f);
}

// ---- fp32 -> bf16 convert (weights) ---------------------------------------
__global__ void k_conv_bf16_v4(const float4* __restrict__ src,
                               ushort4* __restrict__ dst, long n4) {
  long i = blockIdx.x * (long)blockDim.x + threadIdx.x;
  long stride = (long)gridDim.x * blockDim.x;
  for (; i < n4; i += stride) {
    float4 v = src[i];
    ushort4 r;
    r.x = f2bf(v.x); r.y = f2bf(v.y); r.z = f2bf(v.z); r.w = f2bf(v.w);
    dst[i] = r;
  }
}

// ---- GEMM: C[m,n] = sum_k A32[m,k]*B16[n,k]; OutT = float or bf16(u16) ----
#define BM 128
#define BN 128
#define BK 32

template <typename OutT>
__global__ __launch_bounds__(256)
void k_gemm_a32_bt(const float* __restrict__ A, int lda,
                   const uint16_t* __restrict__ B, int ldb,
                   OutT* __restrict__ C, int ldc,
                   int M, int K) {
  __shared__ uint16_t As[BM * BK];
  __shared__ uint16_t Bs[BN * BK];

  const int tid  = threadIdx.x;
  const int lane = tid & 63;
  const int wave = tid >> 6;
  const int lrow = lane & 15;
  const int quad = lane >> 4;
  const int wm = (wave >> 1) * 64;
  const int wn = (wave & 1) * 64;
  const long tm = blockIdx.x;
  const long tn = blockIdx.y;

  f32x4 acc[4][4] = {};

  const int srow = lane >> 2;
  const int scol = (lane & 3) * 8;

  for (int k0 = 0; k0 < K; k0 += BK) {
#pragma unroll
    for (int i = 0; i < 2; ++i) {     // B: async bf16 global->LDS
      int row = i * 64 + wave * 16 + srow;
      long grow = tn * BN + row;
      const uint16_t* gp = B + grow * (long)ldb + k0 + scol;
      uint16_t* lp = &Bs[i * 2048 + wave * 512];
      __builtin_amdgcn_global_load_lds((gbl_void_t*)(uintptr_t)gp,
                                       (lds_void_t*)lp, 16, 0, 0);
    }
#pragma unroll
    for (int i = 0; i < 2; ++i) {     // A: fp32 -> bf16 -> ds_write_b128
      int row = i * 64 + wave * 16 + srow;
      long grow = tm * BM + row;
      if (grow >= M) grow = M - 1;
      const float4* ap = (const float4*)(A + grow * (long)lda + k0 + scol);
      float4 v0 = ap[0], v1 = ap[1];
      bf16x8 r;
      r[0] = (__bf16)v0.x; r[1] = (__bf16)v0.y;
      r[2] = (__bf16)v0.z; r[3] = (__bf16)v0.w;
      r[4] = (__bf16)v1.x; r[5] = (__bf16)v1.y;
      r[6] = (__bf16)v1.z; r[7] = (__bf16)v1.w;
      *(bf16x8*)&As[(i * 64 + wave * 16) * BK + lane * 8] = r;
    }
    __syncthreads();

    bf16x8 a[4], b[4];
#pragma unroll
    for (int f = 0; f < 4; ++f)
      a[f] = *(const bf16x8*)&As[(wm + f * 16 + lrow) * BK + quad * 8];
#pragma unroll
    for (int f = 0; f < 4; ++f)
      b[f] = *(const bf16x8*)&Bs[(wn + f * 16 + lrow) * BK + quad * 8];
#pragma unroll
    for (int fm = 0; fm < 4; ++fm)
#pragma unroll
      for (int fn = 0; fn < 4; ++fn)
        acc[fm][fn] = __builtin_amdgcn_mfma_f32_16x16x32_bf16(
            a[fm], b[fn], acc[fm][fn], 0, 0, 0);
    __syncthreads();
  }

  // C/D layout: col = lane&15, row = quad*4 + reg  [HW-verified]
#pragma unroll
  for (int fm = 0; fm < 4; ++fm) {
#pragma unroll
    for (int fn = 0; fn < 4; ++fn) {
      long col  = tn * BN + wn + fn * 16 + lrow;
      long row0 = tm * BM + wm + fm * 16 + quad * 4;
#pragma unroll
      for (int r = 0; r < 4; ++r) {
        long row = row0 + r;
        if (row < M) {
          float v = acc[fm][fn][r];
          if constexpr (sizeof(OutT) == 2)
            C[row * (long)ldc + col] = (OutT)f2bf(v);
          else
            C[row * (long)ldc + col] = (OutT)v;
        }
      }
    }
  }
}

// ---- wave-per-dot: C[m,n] = dot(A32[m,:K], B16[n,:K]); K in {512,1024} ----
__global__ void k_dot_b16(const float* __restrict__ A, int lda,
                          const uint16_t* __restrict__ B, int ldb,
                          float* __restrict__ C, int ldc,
                          int M, int N, int K) {
  int wid  = (int)((blockIdx.x * (long)blockDim.x + threadIdx.x) >> 6);
  int lane = threadIdx.x & 63;
  if (wid >= M * N) return;
  int m = wid / N, n = wid - m * N;
  const float*    a = A + (long)m * lda;
  const uint16_t* b = B + (long)n * ldb;
  int per = K >> 6;                    // 8 or 16 elems per lane
  int k0  = lane * per;
  float s = 0.f;
  for (int j = 0; j < per; j += 4) {
    float4  av = *(const float4*)(a + k0 + j);
    ushort4 bv = *(const ushort4*)(b + k0 + j);
    s += av.x * bf2f(bv.x) + av.y * bf2f(bv.y)
       + av.z * bf2f(bv.z) + av.w * bf2f(bv.w);
  }
#pragma unroll
  for (int off = 32; off; off >>= 1) s += __shfl_xor(s, off, 64);
  if (lane == 0) C[(long)m * ldc + n] = s;
}

// same but fp32 B (exact path for d=0 forget-child GEMV)
__global__ void k_dot_f32(const float* __restrict__ A, int lda,
                          const float* __restrict__ B, int ldb,
                          float* __restrict__ C, int ldc,
                          int M, int N, int K) {
  int wid  = (int)((blockIdx.x * (long)blockDim.x + threadIdx.x) >> 6);
  int lane = threadIdx.x & 63;
  if (wid >= M * N) return;
  int m = wid / N, n = wid - m * N;
  const float* a = A + (long)m * lda;
  const float* b = B + (long)n * ldb;
  int per = K >> 6;
  int k0  = lane * per;
  float s = 0.f;
  for (int j = 0; j < per; j += 4) {
    float4 av = *(const float4*)(a + k0 + j);
    float4 bv = *(const float4*)(b + k0 + j);
    s += av.x * bv.x + av.y * bv.y + av.z * bv.z + av.w * bv.w;
  }
#pragma unroll
  for (int off = 32; off; off >>= 1) s += __shfl_xor(s, off, 64);
  if (lane == 0) C[(long)m * ldc + n] = s;
}

// ---- fused leaf: gates(bf16 G) -> C_leaf, hsum -> xh[.,512:] ---------------
// thread = (parent pl, 4-wide h quad hq). Never materializes leaf H.
__global__ void k_leaf_fused(const uint16_t* __restrict__ G,   // bf16 [rows,1536]
                             const float* __restrict__ bi,
                             const float* __restrict__ bo,
                             const float* __restrict__ bu,
                             float* __restrict__ Cch,          // [CHUNK,512]
                             float* __restrict__ xh,           // [4096,1024]
                             int pbase, int nPar) {
  long idx = blockIdx.x * (long)blockDim.x + threadIdx.x;
  if (idx >= (long)nPar * 128) return;
  long pl = idx >> 7;
  int  hq = (int)(idx & 127) << 2;
  float4 b_i = *(const float4*)(bi + hq);
  float4 b_o = *(const float4*)(bo + hq);
  float4 b_u = *(const float4*)(bu + hq);
  float hs[4] = {0.f, 0.f, 0.f, 0.f};
#pragma unroll 4
  for (int b = 0; b < 16; ++b) {
    long r = pl * 16 + b;
    const uint16_t* g = G + r * 1536;
    bf16x4 gi = *(const bf16x4*)(g + hq);
    bf16x4 go = *(const bf16x4*)(g + 512 + hq);
    bf16x4 gu = *(const bf16x4*)(g + 1024 + hq);
    float4 c;
    float* cp = &c.x;
    const float* bip = &b_i.x; const float* bop = &b_o.x;
    const float* bup = &b_u.x;
#pragma unroll
    for (int j = 0; j < 4; ++j) {
      float iv = sig_((float)gi[j] + bip[j]);
      float ov = sig_((float)go[j] + bop[j]);
      float uv = tanh_((float)gu[j] + bup[j]);
      float cv = iv * uv;
      cp[j] = cv;
      hs[j] += ov * tanh_(cv);
    }
    *(float4*)(Cch + r * 512 + hq) = c;
  }
  float4 hv = {hs[0], hs[1], hs[2], hs[3]};
  *(float4*)(xh + (long)(pbase + pl) * 1024 + 512 + hq) = hv;
}

// ---- copy x-level-3 rows into xh even halves (once, independent) -----------
__global__ void k_pack_x(const float* __restrict__ x3,
                         float* __restrict__ xh, int n) {
  long idx = blockIdx.x * (long)blockDim.x + threadIdx.x;
  if (idx >= (long)n * 128) return;
  long p = idx >> 7; int hq = (int)(idx & 127) << 2;
  *(float4*)(xh + p * 1024 + hq) = *(const float4*)(x3 + p * 512 + hq);
}

// ---- upper-level h_sum + pack xh (children H fp32) -------------------------
__global__ void k_hsum_xh4(const float* __restrict__ Hc,
                           const float* __restrict__ xd,
                           float* __restrict__ xh, int n) {
  long idx = blockIdx.x * (long)blockDim.x + threadIdx.x;
  if (idx >= (long)n * 128) return;
  long p = idx >> 7; int hq = (int)(idx & 127) << 2;
  const float* hp = Hc + (p << 4) * 512 + hq;
  float4 s = {0.f, 0.f, 0.f, 0.f};
#pragma unroll
  for (int b = 0; b < 16; ++b) {
    float4 v = *(const float4*)(hp + b * 512);
    s.x += v.x; s.y += v.y; s.z += v.z; s.w += v.w;
  }
  *(float4*)(xh + p * 1024 + hq)       = *(const float4*)(xd + p * 512 + hq);
  *(float4*)(xh + p * 1024 + 512 + hq) = s;
}

// ---- forget combine: Fpart[pg] = sum_b sig(fx+fc+bf)*C_child ---------------
__global__ void k_combine4(const float* __restrict__ Fc,   // [nPar*16,512] local
                           const float* __restrict__ Fx,   // [.,512] global
                           const float* __restrict__ bfb,
                           const float* __restrict__ Cc,   // [nPar*16,512] local
                           float* __restrict__ Fpart,
                           int parentBase, int nParents) {
  long idx = blockIdx.x * (long)blockDim.x + threadIdx.x;
  if (idx >= (long)nParents * 128) return;
  long pl = idx >> 7; int hq = (int)(idx & 127) << 2;
  long pg = parentBase + pl;
  float4 fxv = *(const float4*)(Fx + pg * 512 + hq);
  float4 bfv = *(const float4*)(bfb + hq);
  float fx0 = fxv.x + bfv.x, fx1 = fxv.y + bfv.y;
  float fx2 = fxv.z + bfv.z, fx3 = fxv.w + bfv.w;
  float a0 = 0.f, a1 = 0.f, a2 = 0.f, a3 = 0.f;
#pragma unroll 4
  for (int b = 0; b < 16; ++b) {
    long cl = pl * 16 + b;
    float4 f = *(const float4*)(Fc + cl * 512 + hq);
    float4 c = *(const float4*)(Cc + cl * 512 + hq);
    a0 += sig_(fx0 + f.x) * c.x;
    a1 += sig_(fx1 + f.y) * c.y;
    a2 += sig_(fx2 + f.z) * c.z;
    a3 += sig_(fx3 + f.w) * c.w;
  }
  float4 r = {a0, a1, a2, a3};
  *(float4*)(Fpart + pg * 512 + hq) = r;
}

// ---- internal final: C = i*u + Fpart, H = o*tanh(C) ------------------------
__global__ void k_final4(const float* __restrict__ G,      // fp32 [n,1536]
                         const float* __restrict__ Fpart,
                         const float* __restrict__ bi,
                         const float* __restrict__ bo,
                         const float* __restrict__ bu,
                         float* __restrict__ H, float* __restrict__ Cv, int n) {
  long idx = blockIdx.x * (long)blockDim.x + threadIdx.x;
  if (idx >= (long)n * 128) return;
  long p = idx >> 7; int hq = (int)(idx & 127) << 2;
  const float* g = G + p * 1536;
  float4 gi = *(const float4*)(g + hq);
  float4 go = *(const float4*)(g + 512 + hq);
  float4 gu = *(const float4*)(g + 1024 + hq);
  float4 b_i = *(const float4*)(bi + hq);
  float4 b_o = *(const float4*)(bo + hq);
  float4 b_u = *(const float4*)(bu + hq);
  float4 fp = *(const float4*)(Fpart + p * 512 + hq);
  float4 hv, cv;
  const float* gip = &gi.x; const float* gop = &go.x; const float* gup = &gu.x;
  const float* bip = &b_i.x; const float* bop = &b_o.x; const float* bup = &b_u.x;
  const float* fpp = &fp.x;
  float* hvp = &hv.x; float* cvp = &cv.x;
#pragma unroll
  for (int j = 0; j < 4; ++j) {
    float iv = sig_(gip[j] + bip[j]);
    float ov = sig_(gop[j] + bop[j]);
    float uv = tanh_(gup[j] + bup[j]);
    float c  = iv * uv + fpp[j];
    cvp[j] = c;
    hvp[j] = ov * tanh_(c);
  }
  *(float4*)(H  + p * 512 + hq) = hv;
  *(float4*)(Cv + p * 512 + hq) = cv;
}

// ---------------------------------------------------------------------------
extern "C" void kernel_launch(void* const* d_in, const int* in_sizes, int n_in,
                              void* d_out, int out_size, void* d_ws, size_t ws_size,
                              hipStream_t stream) {
  const float* x    = (const float*)d_in[0];
  const float* wi_w = (const float*)d_in[1];
  const float* wi_b = (const float*)d_in[2];
  const float* wf_w = (const float*)d_in[3];
  const float* wf_b = (const float*)d_in[4];
  const float* wo_w = (const float*)d_in[5];
  const float* wo_b = (const float*)d_in[6];
  const float* wu_w = (const float*)d_in[7];
  const float* wu_b = (const float*)d_in[8];
  (void)in_sizes; (void)n_in; (void)out_size; (void)ws_size;

  static const int  sizes[5] = {1, 16, 256, 4096, 65536};
  static const long offs[5]  = {0, 1, 17, 273, 4369};
  const int CHUNK = 16384;          // leaf rows per chunk (4 chunks)
  const int PCH   = CHUNK / 16;     // parents per chunk (1024)

  // ---- workspace (~164 MB of ~572 MB) ----
  char* ws = (char*)d_ws;
  size_t off = 0;
  auto alloc = [&](size_t bytes) -> void* {
    void* p = ws + off;
    off += (bytes + 255) & ~(size_t)255;
    return p;
  };
  uint16_t* Wg   = (uint16_t*)alloc((size_t)1536 * 1024 * 2); // 3.1 MB (i,o,u)
  uint16_t* Wf   = (uint16_t*)alloc((size_t)512 * 1024 * 2);  // 1.0 MB
  void*     Greg = alloc((size_t)CHUNK * 1536 * 2);           // 50.3 MB
  uint16_t* Gbf  = (uint16_t*)Greg;                           // leaf gates (bf16)
  float*    Gf   = (float*)Greg;                              // upper gates (fp32)
  float*    xh   = (float*)alloc((size_t)4096 * 1024 * 4);    // 16.8 MB
  float*    Cch  = (float*)alloc((size_t)CHUNK * 512 * 4);    // 33.5 MB
  float*    Fx   = (float*)alloc((size_t)4096 * 512 * 4);     // 8.4 MB
  float*    Fpart= (float*)alloc((size_t)4096 * 512 * 4);     // 8.4 MB
  float*    Fc   = (float*)alloc((size_t)CHUNK * 512 * 4);    // 33.5 MB
  float*    HupA = (float*)alloc((size_t)4096 * 512 * 4);     // 8.4 MB
  float*    CupA = (float*)alloc((size_t)4096 * 512 * 4);     // 8.4 MB
  float*    HupB = (float*)alloc((size_t)256 * 512 * 4);      // 0.5 MB
  float*    CupB = (float*)alloc((size_t)256 * 512 * 4);      // 0.5 MB

  auto conv = [&](const float* s, uint16_t* d, long n) {
    long n4 = n >> 2;
    int grid = (int)((n4 + 255) / 256);
    if (grid > 4096) grid = 4096;
    k_conv_bf16_v4<<<grid, 256, 0, stream>>>((const float4*)s, (ushort4*)d, n4);
  };
  conv(wi_w, Wg,                (long)512 * 1024);
  conv(wo_w, Wg + 512 * 1024,   (long)512 * 1024);
  conv(wu_w, Wg + 1024 * 1024,  (long)512 * 1024);
  conv(wf_w, Wf,                (long)512 * 1024);

  auto gemm_f32 = [&](const float* A, int lda, const uint16_t* B, int ldb,
                      float* Cp, int ldc, int M, int N, int K) {
    dim3 grid((M + BM - 1) / BM, N / BN);
    k_gemm_a32_bt<float><<<grid, 256, 0, stream>>>(A, lda, B, ldb, Cp, ldc, M, K);
  };
  auto gemm_b16 = [&](const float* A, int lda, const uint16_t* B, int ldb,
                      uint16_t* Cp, int ldc, int M, int N, int K) {
    dim3 grid((M + BM - 1) / BM, N / BN);
    k_gemm_a32_bt<uint16_t><<<grid, 256, 0, stream>>>(A, lda, B, ldb, Cp, ldc, M, K);
  };
  auto dotb = [&](const float* A, int lda, const uint16_t* B, int ldb,
                  float* Cp, int ldc, int M, int N, int K) {
    long waves = (long)M * N;
    int blocks = (int)((waves * 64 + 255) / 256);
    k_dot_b16<<<blocks, 256, 0, stream>>>(A, lda, B, ldb, Cp, ldc, M, N, K);
  };
  auto blks = [](long n) { return (int)((n + 255) / 256); };

  const float* x3 = x + offs[3] * 512;

  // x-half of level-3 xh (independent of leaves)
  k_pack_x<<<blks(4096 * 128), 256, 0, stream>>>(x3, xh, 4096);
  // Fx for level-3 parents
  gemm_f32(x3, 512, Wf, 1024, Fx, 512, 4096, 512, 512);

  // ---- leaf level, 4 fused chunks ----
  for (int c = 0; c < 65536 / CHUNK; ++c) {
    long base  = (long)c * CHUNK;
    int  pbase = c * PCH;
    // gates preact, bf16 out (h=0 at leaves => K=512, x-half of Wg)
    gemm_b16(x + (offs[4] + base) * 512, 512, Wg, 1024, Gbf, 1536,
             CHUNK, 1536, 512);
    k_leaf_fused<<<blks((long)PCH * 128), 256, 0, stream>>>(
        Gbf, wi_b, wo_b, wu_b, Cch, xh, pbase, PCH);
    // fc: [CHUNK,512] x Wf[:,512:]^T
    gemm_f32(Cch, 512, Wf + 512, 1024, Fc, 512, CHUNK, 512, 512);
    k_combine4<<<blks((long)PCH * 128), 256, 0, stream>>>(
        Fc, Fx, wf_b, Cch, Fpart, pbase, PCH);
  }

  // ---- level 3 finalize ----
  gemm_f32(xh, 1024, Wg, 1024, Gf, 1536, 4096, 1536, 1024);
  k_final4<<<blks(4096 * 128), 256, 0, stream>>>(
      Gf, Fpart, wi_b, wo_b, wu_b, HupA, CupA, 4096);

  // ---- levels 2,1,0 ----
  float* Hcs[3] = {HupA, HupB, HupA};
  float* Ccs[3] = {CupA, CupB, CupA};
  float* Hos[3] = {HupB, HupA, (float*)d_out};
  float* Cos[3] = {CupB, CupA, (float*)d_out + 512};
  for (int j = 0; j < 3; ++j) {
    int d   = 2 - j;
    int n   = sizes[d];
    int nch = sizes[d + 1];
    const float* xd = x + offs[d] * 512;

    k_hsum_xh4<<<blks((long)n * 128), 256, 0, stream>>>(Hcs[j], xd, xh, n);

    // gates
    if (n >= 256) gemm_f32(xh, 1024, Wg, 1024, Gf, 1536, n, 1536, 1024);
    else          dotb(xh, 1024, Wg, 1024, Gf, 1536, n, 1536, 1024);
    // fx (always small M here: 256,16,1)
    dotb(xd, 512, Wf, 1024, Fx, 512, n, 512, 512);
    // fc on children
    if (nch >= 4096) {
      gemm_f32(Ccs[j], 512, Wf + 512, 1024, Fc, 512, nch, 512, 512);
    } else if (d >= 1) {
      dotb(Ccs[j], 512, Wf + 512, 1024, Fc, 512, nch, 512, 512);
    } else {
      // d=0: exact fp32 (child C magnitudes are largest here)
      long waves = (long)nch * 512;
      k_dot_f32<<<(int)((waves * 64 + 255) / 256), 256, 0, stream>>>(
          Ccs[j], 512, wf_w + 512, 1024, Fc, 512, nch, 512, 512);
    }
    k_combine4<<<blks((long)n * 128), 256, 0, stream>>>(
        Fc, Fx, wf_b, Ccs[j], Fpart, 0, n);
    k_final4<<<blks((long)n * 128), 256, 0, stream>>>(
        Gf, Fpart, wi_b, wo_b, wu_b, Hos[j], Cos[j], n);
  }
}

// Round 4
// 727.912 us; speedup vs baseline: 1.9757x; 1.1645x over previous
//
#include <hip/hip_runtime.h>
#include <stdint.h>
#include <stddef.h>

// ---------------------------------------------------------------------------
// CSTreeLSTM on gfx950. Levels 1,16,256,4096,65536 (x offsets 0,1,17,273,4369),
// IN=HID=512. Round 4: de-chunked leaf level (full M=65536 GEMMs), forget
// combine fused into the fc GEMM epilogue (one 16x16 frag = one parent's 16
// children; shfl-xor quad reduction), all-bf16 GEMM operands (m97 pattern).
// Workspace ~400 MB of ~573 MB.
// ---------------------------------------------------------------------------

typedef __bf16 bf16x8 __attribute__((ext_vector_type(8)));
typedef __bf16 bf16x4 __attribute__((ext_vector_type(4)));
typedef float  f32x4  __attribute__((ext_vector_type(4)));
typedef void __attribute__((address_space(3))) lds_void_t;
typedef void __attribute__((address_space(1))) gbl_void_t;

__device__ __forceinline__ uint16_t f2bf(float f) {
  union { float f; uint32_t u; } v; v.f = f;
  return (uint16_t)((v.u + 0x7fffu + ((v.u >> 16) & 1u)) >> 16);
}
__device__ __forceinline__ float bf2f(uint16_t u) {
  union { uint32_t u; float f; } v; v.u = (uint32_t)u << 16;
  return v.f;
}
__device__ __forceinline__ float sig_(float x) {
  return 1.0f / (1.0f + __expf(-x));
}
__device__ __forceinline__ float tanh_(float x) {
  x = fminf(15.f, fmaxf(-15.f, x));
  float e = __expf(2.f * x);
  return (e - 1.f) / (e + 1.f);
}

// ---- fp32 -> bf16 convert --------------------------------------------------
__global__ void k_conv_bf16_v4(const float4* __restrict__ src,
                               ushort4* __restrict__ dst, long n4) {
  long i = blockIdx.x * (long)blockDim.x + threadIdx.x;
  long stride = (long)gridDim.x * blockDim.x;
  for (; i < n4; i += stride) {
    float4 v = src[i];
    ushort4 r;
    r.x = f2bf(v.x); r.y = f2bf(v.y); r.z = f2bf(v.z); r.w = f2bf(v.w);
    dst[i] = r;
  }
}

#define BM 128
#define BN 128
#define BK 32

// ---- pure-bf16 GEMM: C[m,n] = sum_k A[m,k]*B[n,k]; M,N multiples of 128 ----
template <typename OutT>
__global__ __launch_bounds__(256)
void k_gemm_bt(const uint16_t* __restrict__ A, int lda,
               const uint16_t* __restrict__ B, int ldb,
               OutT* __restrict__ C, int ldc, int K) {
  __shared__ uint16_t As[BM * BK];
  __shared__ uint16_t Bs[BN * BK];

  const int tid  = threadIdx.x;
  const int lane = tid & 63;
  const int wave = tid >> 6;
  const int lrow = lane & 15;
  const int quad = lane >> 4;
  const int wm = (wave >> 1) * 64;
  const int wn = (wave & 1) * 64;
  const long tm = blockIdx.x;
  const long tn = blockIdx.y;

  f32x4 acc[4][4] = {};

  const int srow = lane >> 2;
  const int scol = (lane & 3) * 8;

  for (int k0 = 0; k0 < K; k0 += BK) {
#pragma unroll
    for (int i = 0; i < 2; ++i) {
      int row = i * 64 + wave * 16 + srow;
      const uint16_t* gp = A + (tm * BM + row) * (long)lda + k0 + scol;
      uint16_t* lp = &As[i * 2048 + wave * 512];
      __builtin_amdgcn_global_load_lds((gbl_void_t*)(uintptr_t)gp,
                                       (lds_void_t*)lp, 16, 0, 0);
    }
#pragma unroll
    for (int i = 0; i < 2; ++i) {
      int row = i * 64 + wave * 16 + srow;
      const uint16_t* gp = B + (tn * BN + row) * (long)ldb + k0 + scol;
      uint16_t* lp = &Bs[i * 2048 + wave * 512];
      __builtin_amdgcn_global_load_lds((gbl_void_t*)(uintptr_t)gp,
                                       (lds_void_t*)lp, 16, 0, 0);
    }
    __syncthreads();

    bf16x8 a[4], b[4];
#pragma unroll
    for (int f = 0; f < 4; ++f)
      a[f] = *(const bf16x8*)&As[(wm + f * 16 + lrow) * BK + quad * 8];
#pragma unroll
    for (int f = 0; f < 4; ++f)
      b[f] = *(const bf16x8*)&Bs[(wn + f * 16 + lrow) * BK + quad * 8];
#pragma unroll
    for (int fm = 0; fm < 4; ++fm)
#pragma unroll
      for (int fn = 0; fn < 4; ++fn)
        acc[fm][fn] = __builtin_amdgcn_mfma_f32_16x16x32_bf16(
            a[fm], b[fn], acc[fm][fn], 0, 0, 0);
    __syncthreads();
  }

  // C/D layout: col = lane&15, row = quad*4 + reg  [HW-verified]
#pragma unroll
  for (int fm = 0; fm < 4; ++fm) {
#pragma unroll
    for (int fn = 0; fn < 4; ++fn) {
      long col  = tn * BN + wn + fn * 16 + lrow;
      long row0 = tm * BM + wm + fm * 16 + quad * 4;
#pragma unroll
      for (int r = 0; r < 4; ++r) {
        float v = acc[fm][fn][r];
        if constexpr (sizeof(OutT) == 2)
          C[(row0 + r) * (long)ldc + col] = (OutT)f2bf(v);
        else
          C[(row0 + r) * (long)ldc + col] = (OutT)v;
      }
    }
  }
}

// ---- fc GEMM + fused forget-combine ---------------------------------------
// A = Cbf [M,512] bf16 child cells; B = Wf_c [512,1024-ld]; N=512.
// Tile rows = 128 children = 8 parents; one 16x16 frag = one parent's 16
// children x 16 cols. Epilogue: Fpart[pg,col] = sum_b sig(Fx+bf+fc)*C_child.
__global__ __launch_bounds__(256)
void k_fc_combine(const uint16_t* __restrict__ Cbf,
                  const uint16_t* __restrict__ Wfc, int ldb,
                  const float* __restrict__ Fx,
                  const float* __restrict__ bfb,
                  float* __restrict__ Fpart) {
  __shared__ uint16_t As[BM * BK];
  __shared__ uint16_t Bs[BN * BK];

  const int tid  = threadIdx.x;
  const int lane = tid & 63;
  const int wave = tid >> 6;
  const int lrow = lane & 15;
  const int quad = lane >> 4;
  const int wm = (wave >> 1) * 64;
  const int wn = (wave & 1) * 64;
  const long tm = blockIdx.x;
  const long tn = blockIdx.y;
  const int K = 512, lda = 512;

  f32x4 acc[4][4] = {};
  const int srow = lane >> 2;
  const int scol = (lane & 3) * 8;

  for (int k0 = 0; k0 < K; k0 += BK) {
#pragma unroll
    for (int i = 0; i < 2; ++i) {
      int row = i * 64 + wave * 16 + srow;
      const uint16_t* gp = Cbf + (tm * BM + row) * (long)lda + k0 + scol;
      uint16_t* lp = &As[i * 2048 + wave * 512];
      __builtin_amdgcn_global_load_lds((gbl_void_t*)(uintptr_t)gp,
                                       (lds_void_t*)lp, 16, 0, 0);
    }
#pragma unroll
    for (int i = 0; i < 2; ++i) {
      int row = i * 64 + wave * 16 + srow;
      const uint16_t* gp = Wfc + (tn * BN + row) * (long)ldb + k0 + scol;
      uint16_t* lp = &Bs[i * 2048 + wave * 512];
      __builtin_amdgcn_global_load_lds((gbl_void_t*)(uintptr_t)gp,
                                       (lds_void_t*)lp, 16, 0, 0);
    }
    __syncthreads();

    bf16x8 a[4], b[4];
#pragma unroll
    for (int f = 0; f < 4; ++f)
      a[f] = *(const bf16x8*)&As[(wm + f * 16 + lrow) * BK + quad * 8];
#pragma unroll
    for (int f = 0; f < 4; ++f)
      b[f] = *(const bf16x8*)&Bs[(wn + f * 16 + lrow) * BK + quad * 8];
#pragma unroll
    for (int fm = 0; fm < 4; ++fm)
#pragma unroll
      for (int fn = 0; fn < 4; ++fn)
        acc[fm][fn] = __builtin_amdgcn_mfma_f32_16x16x32_bf16(
            a[fm], b[fn], acc[fm][fn], 0, 0, 0);
    __syncthreads();
  }

  // fused combine epilogue
#pragma unroll
  for (int fm = 0; fm < 4; ++fm) {
    long pg   = tm * 8 + (wm >> 4) + fm;            // parent index
    long row0 = tm * BM + wm + fm * 16 + quad * 4;  // child rows (this lane)
#pragma unroll
    for (int fn = 0; fn < 4; ++fn) {
      long col = tn * BN + wn + fn * 16 + lrow;
      float fx = Fx[pg * 512 + col] + bfb[col];
      float t = 0.f;
#pragma unroll
      for (int r = 0; r < 4; ++r)
        t += sig_(fx + acc[fm][fn][r]) * bf2f(Cbf[(row0 + r) * 512 + col]);
      t += __shfl_xor(t, 16, 64);   // quads share col; rows differ
      t += __shfl_xor(t, 32, 64);
      if (quad == 0) Fpart[pg * 512 + col] = t;
    }
  }
}

// ---- wave-per-dot, bf16 x bf16 -> fp32 (starved shapes) --------------------
__global__ void k_dot_bb(const uint16_t* __restrict__ A, int lda,
                         const uint16_t* __restrict__ B, int ldb,
                         float* __restrict__ C, int ldc,
                         int M, int N, int K) {
  int wid  = (int)((blockIdx.x * (long)blockDim.x + threadIdx.x) >> 6);
  int lane = threadIdx.x & 63;
  if (wid >= M * N) return;
  int m = wid / N, n = wid - m * N;
  const uint16_t* a = A + (long)m * lda;
  const uint16_t* b = B + (long)n * ldb;
  int per = K >> 6;
  int k0  = lane * per;
  float s = 0.f;
  for (int j = 0; j < per; j += 4) {
    ushort4 av = *(const ushort4*)(a + k0 + j);
    ushort4 bv = *(const ushort4*)(b + k0 + j);
    s += bf2f(av.x) * bf2f(bv.x) + bf2f(av.y) * bf2f(bv.y)
       + bf2f(av.z) * bf2f(bv.z) + bf2f(av.w) * bf2f(bv.w);
  }
#pragma unroll
  for (int off = 32; off; off >>= 1) s += __shfl_xor(s, off, 64);
  if (lane == 0) C[(long)m * ldc + n] = s;
}

// ---- wave-per-dot, fp32 x fp32 (exact d=0 fc) ------------------------------
__global__ void k_dot_f32(const float* __restrict__ A, int lda,
                          const float* __restrict__ B, int ldb,
                          float* __restrict__ C, int ldc,
                          int M, int N, int K) {
  int wid  = (int)((blockIdx.x * (long)blockDim.x + threadIdx.x) >> 6);
  int lane = threadIdx.x & 63;
  if (wid >= M * N) return;
  int m = wid / N, n = wid - m * N;
  const float* a = A + (long)m * lda;
  const float* b = B + (long)n * ldb;
  int per = K >> 6;
  int k0  = lane * per;
  float s = 0.f;
  for (int j = 0; j < per; j += 4) {
    float4 av = *(const float4*)(a + k0 + j);
    float4 bv = *(const float4*)(b + k0 + j);
    s += av.x * bv.x + av.y * bv.y + av.z * bv.z + av.w * bv.w;
  }
#pragma unroll
  for (int off = 32; off; off >>= 1) s += __shfl_xor(s, off, 64);
  if (lane == 0) C[(long)m * ldc + n] = s;
}

// ---- fused leaf: bf16 gates -> Cbf (bf16), hsum -> xh[.,512:] (bf16) -------
__global__ void k_leaf_fused(const uint16_t* __restrict__ G,  // [rows,1536]
                             const float* __restrict__ bi,
                             const float* __restrict__ bo,
                             const float* __restrict__ bu,
                             uint16_t* __restrict__ Cbf,      // [65536,512]
                             uint16_t* __restrict__ xh,       // [4096,1024]
                             int nPar) {
  long idx = blockIdx.x * (long)blockDim.x + threadIdx.x;
  if (idx >= (long)nPar * 128) return;
  long pl = idx >> 7;
  int  hq = (int)(idx & 127) << 2;
  float4 b_i = *(const float4*)(bi + hq);
  float4 b_o = *(const float4*)(bo + hq);
  float4 b_u = *(const float4*)(bu + hq);
  const float* bip = &b_i.x; const float* bop = &b_o.x;
  const float* bup = &b_u.x;
  float hs[4] = {0.f, 0.f, 0.f, 0.f};
#pragma unroll 4
  for (int b = 0; b < 16; ++b) {
    long r = pl * 16 + b;
    const uint16_t* g = G + r * 1536;
    bf16x4 gi = *(const bf16x4*)(g + hq);
    bf16x4 go = *(const bf16x4*)(g + 512 + hq);
    bf16x4 gu = *(const bf16x4*)(g + 1024 + hq);
    ushort4 cw;
    unsigned short* cwp = &cw.x;
#pragma unroll
    for (int j = 0; j < 4; ++j) {
      float iv = sig_((float)gi[j] + bip[j]);
      float ov = sig_((float)go[j] + bop[j]);
      float uv = tanh_((float)gu[j] + bup[j]);
      float cv = iv * uv;
      cwp[j] = f2bf(cv);
      hs[j] += ov * tanh_(cv);
    }
    *(ushort4*)(Cbf + r * 512 + hq) = cw;
  }
  ushort4 hw = {f2bf(hs[0]), f2bf(hs[1]), f2bf(hs[2]), f2bf(hs[3])};
  *(ushort4*)(xh + pl * 1024 + 512 + hq) = hw;
}

// ---- copy bf16 x rows into xh even halves ----------------------------------
__global__ void k_pack_x(const uint16_t* __restrict__ xb,
                         uint16_t* __restrict__ xh, int n) {
  long idx = blockIdx.x * (long)blockDim.x + threadIdx.x;
  if (idx >= (long)n * 128) return;
  long p = idx >> 7; int hq = (int)(idx & 127) << 2;
  *(ushort4*)(xh + p * 1024 + hq) = *(const ushort4*)(xb + p * 512 + hq);
}

// ---- upper-level h_sum + pack xh (children H fp32, x bf16) -----------------
__global__ void k_hsum_xh4(const float* __restrict__ Hc,
                           const uint16_t* __restrict__ xd,
                           uint16_t* __restrict__ xh, int n) {
  long idx = blockIdx.x * (long)blockDim.x + threadIdx.x;
  if (idx >= (long)n * 128) return;
  long p = idx >> 7; int hq = (int)(idx & 127) << 2;
  const float* hp = Hc + (p << 4) * 512 + hq;
  float4 s = {0.f, 0.f, 0.f, 0.f};
#pragma unroll
  for (int b = 0; b < 16; ++b) {
    float4 v = *(const float4*)(hp + b * 512);
    s.x += v.x; s.y += v.y; s.z += v.z; s.w += v.w;
  }
  *(ushort4*)(xh + p * 1024 + hq) = *(const ushort4*)(xd + p * 512 + hq);
  ushort4 hw = {f2bf(s.x), f2bf(s.y), f2bf(s.z), f2bf(s.w)};
  *(ushort4*)(xh + p * 1024 + 512 + hq) = hw;
}

// ---- separate combine (d=0 exact path only) --------------------------------
__global__ void k_combine4(const float* __restrict__ Fc,
                           const float* __restrict__ Fx,
                           const float* __restrict__ bfb,
                           const float* __restrict__ Cc,
                           float* __restrict__ Fpart, int nParents) {
  long idx = blockIdx.x * (long)blockDim.x + threadIdx.x;
  if (idx >= (long)nParents * 128) return;
  long pl = idx >> 7; int hq = (int)(idx & 127) << 2;
  float4 fxv = *(const float4*)(Fx + pl * 512 + hq);
  float4 bfv = *(const float4*)(bfb + hq);
  float fx0 = fxv.x + bfv.x, fx1 = fxv.y + bfv.y;
  float fx2 = fxv.z + bfv.z, fx3 = fxv.w + bfv.w;
  float a0 = 0.f, a1 = 0.f, a2 = 0.f, a3 = 0.f;
#pragma unroll 4
  for (int b = 0; b < 16; ++b) {
    long cl = pl * 16 + b;
    float4 f = *(const float4*)(Fc + cl * 512 + hq);
    float4 c = *(const float4*)(Cc + cl * 512 + hq);
    a0 += sig_(fx0 + f.x) * c.x;
    a1 += sig_(fx1 + f.y) * c.y;
    a2 += sig_(fx2 + f.z) * c.z;
    a3 += sig_(fx3 + f.w) * c.w;
  }
  float4 r = {a0, a1, a2, a3};
  *(float4*)(Fpart + pl * 512 + hq) = r;
}

// ---- internal final: C = i*u + Fpart, H = o*tanh(C); writes fp32 + bf16 C --
__global__ void k_final4(const float* __restrict__ G,
                         const float* __restrict__ Fpart,
                         const float* __restrict__ bi,
                         const float* __restrict__ bo,
                         const float* __restrict__ bu,
                         float* __restrict__ H, float* __restrict__ Cv,
                         uint16_t* __restrict__ Cbf, int n) {
  long idx = blockIdx.x * (long)blockDim.x + threadIdx.x;
  if (idx >= (long)n * 128) return;
  long p = idx >> 7; int hq = (int)(idx & 127) << 2;
  const float* g = G + p * 1536;
  float4 gi = *(const float4*)(g + hq);
  float4 go = *(const float4*)(g + 512 + hq);
  float4 gu = *(const float4*)(g + 1024 + hq);
  float4 b_i = *(const float4*)(bi + hq);
  float4 b_o = *(const float4*)(bo + hq);
  float4 b_u = *(const float4*)(bu + hq);
  float4 fp = *(const float4*)(Fpart + p * 512 + hq);
  const float* gip = &gi.x; const float* gop = &go.x; const float* gup = &gu.x;
  const float* bip = &b_i.x; const float* bop = &b_o.x; const float* bup = &b_u.x;
  const float* fpp = &fp.x;
  float4 hv, cv;
  float* hvp = &hv.x; float* cvp = &cv.x;
  ushort4 cw; unsigned short* cwp = &cw.x;
#pragma unroll
  for (int j = 0; j < 4; ++j) {
    float iv = sig_(gip[j] + bip[j]);
    float ov = sig_(gop[j] + bop[j]);
    float uv = tanh_(gup[j] + bup[j]);
    float c  = iv * uv + fpp[j];
    cvp[j] = c;
    cwp[j] = f2bf(c);
    hvp[j] = ov * tanh_(c);
  }
  *(float4*)(H  + p * 512 + hq) = hv;
  *(float4*)(Cv + p * 512 + hq) = cv;
  *(ushort4*)(Cbf + p * 512 + hq) = cw;
}

// ---------------------------------------------------------------------------
extern "C" void kernel_launch(void* const* d_in, const int* in_sizes, int n_in,
                              void* d_out, int out_size, void* d_ws, size_t ws_size,
                              hipStream_t stream) {
  const float* x    = (const float*)d_in[0];
  const float* wi_w = (const float*)d_in[1];
  const float* wi_b = (const float*)d_in[2];
  const float* wf_w = (const float*)d_in[3];
  const float* wf_b = (const float*)d_in[4];
  const float* wo_w = (const float*)d_in[5];
  const float* wo_b = (const float*)d_in[6];
  const float* wu_w = (const float*)d_in[7];
  const float* wu_b = (const float*)d_in[8];
  (void)in_sizes; (void)n_in; (void)out_size; (void)ws_size;

  static const long offs[5] = {0, 1, 17, 273, 4369};
  const long NTOT = 69905;

  // ---- workspace (~400 MB of ~573 MB) ----
  char* ws = (char*)d_ws;
  size_t off = 0;
  auto alloc = [&](size_t bytes) -> void* {
    void* p = ws + off;
    off += (bytes + 255) & ~(size_t)255;
    return p;
  };
  uint16_t* Xbf  = (uint16_t*)alloc(NTOT * 512 * 2);            // 71.6 MB
  uint16_t* Wg   = (uint16_t*)alloc((size_t)1536 * 1024 * 2);   // 3.1 MB
  uint16_t* Wf   = (uint16_t*)alloc((size_t)512 * 1024 * 2);    // 1.0 MB
  void*     Greg = alloc((size_t)65536 * 1536 * 2);             // 201.3 MB
  uint16_t* G    = (uint16_t*)Greg;          // leaf gates (bf16)
  float*    Gf   = (float*)Greg;             // upper gates (fp32, <=4096 rows)
  uint16_t* xh   = (uint16_t*)alloc((size_t)4096 * 1024 * 2);   // 8.4 MB
  uint16_t* Cbf  = (uint16_t*)alloc((size_t)65536 * 512 * 2);   // 67.1 MB
  uint16_t* CbfU = (uint16_t*)alloc((size_t)4096 * 512 * 2);    // 4.2 MB
  float*    Fx   = (float*)alloc((size_t)4096 * 512 * 4);       // 8.4 MB
  float*    Fpart= (float*)alloc((size_t)4096 * 512 * 4);       // 8.4 MB
  float*    Fc   = (float*)alloc((size_t)16 * 512 * 4);         // 0.03 MB
  float*    HupA = (float*)alloc((size_t)4096 * 512 * 4);       // 8.4 MB
  float*    CupA = (float*)alloc((size_t)4096 * 512 * 4);       // 8.4 MB
  float*    HupB = (float*)alloc((size_t)256 * 512 * 4);        // 0.5 MB
  float*    CupB = (float*)alloc((size_t)256 * 512 * 4);        // 0.5 MB

  auto conv = [&](const float* s, uint16_t* d, long n) {
    long n4 = n >> 2;
    int grid = (int)((n4 + 255) / 256);
    if (grid > 8192) grid = 8192;
    k_conv_bf16_v4<<<grid, 256, 0, stream>>>((const float4*)s, (ushort4*)d, n4);
  };
  auto gemm_f = [&](const uint16_t* A, int lda, const uint16_t* B, int ldb,
                    float* Cp, int ldc, int M, int N, int K) {
    dim3 grid(M / BM, N / BN);
    k_gemm_bt<float><<<grid, 256, 0, stream>>>(A, lda, B, ldb, Cp, ldc, K);
  };
  auto gemm_h = [&](const uint16_t* A, int lda, const uint16_t* B, int ldb,
                    uint16_t* Cp, int ldc, int M, int N, int K) {
    dim3 grid(M / BM, N / BN);
    k_gemm_bt<uint16_t><<<grid, 256, 0, stream>>>(A, lda, B, ldb, Cp, ldc, K);
  };
  auto fcc = [&](const uint16_t* Cchild, int M) {
    dim3 grid(M / BM, 4);
    k_fc_combine<<<grid, 256, 0, stream>>>(Cchild, Wf + 512, 1024, Fx, wf_b,
                                           Fpart);
  };
  auto dotbb = [&](const uint16_t* A, int lda, const uint16_t* B, int ldb,
                   float* Cp, int ldc, int M, int N, int K) {
    long waves = (long)M * N;
    int blocks = (int)((waves * 64 + 255) / 256);
    k_dot_bb<<<blocks, 256, 0, stream>>>(A, lda, B, ldb, Cp, ldc, M, N, K);
  };
  auto blks = [](long n) { return (int)((n + 255) / 256); };

  // ---- converts ----
  conv(x,    Xbf, NTOT * 512);
  conv(wi_w, Wg,                (long)512 * 1024);
  conv(wo_w, Wg + 512 * 1024,   (long)512 * 1024);
  conv(wu_w, Wg + 1024 * 1024,  (long)512 * 1024);
  conv(wf_w, Wf,                (long)512 * 1024);

  const uint16_t* X4 = Xbf + offs[4] * 512;
  const uint16_t* X3 = Xbf + offs[3] * 512;

  // ---- leaf level (M=65536, un-chunked) ----
  gemm_h(X4, 512, Wg, 1024, G, 1536, 65536, 1536, 512);     // gates preact
  k_leaf_fused<<<blks(4096L * 128), 256, 0, stream>>>(
      G, wi_b, wo_b, wu_b, Cbf, xh, 4096);
  k_pack_x<<<blks(4096L * 128), 256, 0, stream>>>(X3, xh, 4096);
  gemm_f(X3, 512, Wf, 1024, Fx, 512, 4096, 512, 512);       // Fx level-3
  fcc(Cbf, 65536);                                          // fc + combine

  // ---- level 3 (n=4096) ----
  gemm_f(xh, 1024, Wg, 1024, Gf, 1536, 4096, 1536, 1024);
  k_final4<<<blks(4096L * 128), 256, 0, stream>>>(
      Gf, Fpart, wi_b, wo_b, wu_b, HupA, CupA, CbfU, 4096);

  // ---- level 2 (n=256, nch=4096) ----
  k_hsum_xh4<<<blks(256L * 128), 256, 0, stream>>>(
      HupA, Xbf + offs[2] * 512, xh, 256);
  gemm_f(xh, 1024, Wg, 1024, Gf, 1536, 256, 1536, 1024);
  dotbb(Xbf + offs[2] * 512, 512, Wf, 1024, Fx, 512, 256, 512, 512);
  fcc(CbfU, 4096);
  k_final4<<<blks(256L * 128), 256, 0, stream>>>(
      Gf, Fpart, wi_b, wo_b, wu_b, HupB, CupB, CbfU, 256);  // overwrites rows 0..255 after fcc read

  // ---- level 1 (n=16, nch=256) ----
  k_hsum_xh4<<<blks(16L * 128), 256, 0, stream>>>(
      HupB, Xbf + offs[1] * 512, xh, 16);
  dotbb(xh, 1024, Wg, 1024, Gf, 1536, 16, 1536, 1024);
  dotbb(Xbf + offs[1] * 512, 512, Wf, 1024, Fx, 512, 16, 512, 512);
  fcc(CbfU, 256);
  k_final4<<<blks(16L * 128), 256, 0, stream>>>(
      Gf, Fpart, wi_b, wo_b, wu_b, HupA, CupA, CbfU, 16);   // C1 fp32 in CupA

  // ---- level 0 (n=1, nch=16; exact fp32 fc path) ----
  k_hsum_xh4<<<blks(128), 256, 0, stream>>>(
      HupA, Xbf + offs[0] * 512, xh, 1);
  dotbb(xh, 1024, Wg, 1024, Gf, 1536, 1, 1536, 1024);
  dotbb(Xbf + offs[0] * 512, 512, Wf, 1024, Fx, 512, 1, 512, 512);
  {
    long waves = 16L * 512;
    k_dot_f32<<<(int)((waves * 64 + 255) / 256), 256, 0, stream>>>(
        CupA, 512, wf_w + 512, 1024, Fc, 512, 16, 512, 512);
  }
  k_combine4<<<1, 256, 0, stream>>>(Fc, Fx, wf_b, CupA, Fpart, 1);
  k_final4<<<1, 256, 0, stream>>>(
      Gf, Fpart, wi_b, wo_b, wu_b,
      (float*)d_out, (float*)d_out + 512, CbfU, 1);
}

// Round 5
// 681.648 us; speedup vs baseline: 2.1098x; 1.0679x over previous
//
#include <hip/hip_runtime.h>
#include <stdint.h>
#include <stddef.h>

// ---------------------------------------------------------------------------
// CSTreeLSTM on gfx950. Levels 1,16,256,4096,65536 (x offsets 0,1,17,273,4369).
// Round 5: gates GEMM fused with LSTM epilogue + per-parent hsum (k_level):
// 3 accumulator sets (i,o,u) over a 128x64 tile; no G preact buffer at all.
// One batched Fx GEMM for all upper levels (node ids 0..4368 contiguous).
// ---------------------------------------------------------------------------

typedef __bf16 bf16x8 __attribute__((ext_vector_type(8)));
typedef float  f32x4  __attribute__((ext_vector_type(4)));
typedef void __attribute__((address_space(3))) lds_void_t;
typedef void __attribute__((address_space(1))) gbl_void_t;

__device__ __forceinline__ uint16_t f2bf(float f) {
  union { float f; uint32_t u; } v; v.f = f;
  return (uint16_t)((v.u + 0x7fffu + ((v.u >> 16) & 1u)) >> 16);
}
__device__ __forceinline__ float bf2f(uint16_t u) {
  union { uint32_t u; float f; } v; v.u = (uint32_t)u << 16;
  return v.f;
}
__device__ __forceinline__ float sig_(float x) {
  return 1.0f / (1.0f + __expf(-x));
}
__device__ __forceinline__ float tanh_(float x) {
  x = fminf(15.f, fmaxf(-15.f, x));
  float e = __expf(2.f * x);
  return (e - 1.f) / (e + 1.f);
}

// ---- converts --------------------------------------------------------------
__global__ void k_conv_x(const float4* __restrict__ src,
                         ushort4* __restrict__ dst, long n4) {
  long i = blockIdx.x * (long)blockDim.x + threadIdx.x;
  long stride = (long)gridDim.x * blockDim.x;
  for (; i < n4; i += stride) {
    float4 v = src[i];
    ushort4 r;
    r.x = f2bf(v.x); r.y = f2bf(v.y); r.z = f2bf(v.z); r.w = f2bf(v.w);
    dst[i] = r;
  }
}
// four 512x1024 weight mats -> contiguous dst (Wi,Wo,Wu,Wf)
__global__ void k_conv_w(const float4* __restrict__ w0,
                         const float4* __restrict__ w1,
                         const float4* __restrict__ w2,
                         const float4* __restrict__ w3,
                         ushort4* __restrict__ dst) {
  const long per4 = (long)512 * 1024 / 4;  // 131072
  long i = blockIdx.x * (long)blockDim.x + threadIdx.x;
  long stride = (long)gridDim.x * blockDim.x;
  for (; i < 4 * per4; i += stride) {
    long seg = i / per4, off2 = i - seg * per4;
    const float4* s = (seg == 0) ? w0 : (seg == 1) ? w1 : (seg == 2) ? w2 : w3;
    float4 v = s[off2];
    ushort4 r;
    r.x = f2bf(v.x); r.y = f2bf(v.y); r.z = f2bf(v.z); r.w = f2bf(v.w);
    dst[i] = r;
  }
}

#define BM 128
#define BN 128
#define BK 32

// ---- plain bf16 GEMM (FxAll only): C[m,n]=sum_k A[m,k]*B[n,k], fp32 out ----
__global__ __launch_bounds__(256)
void k_gemm_bt(const uint16_t* __restrict__ A, int lda,
               const uint16_t* __restrict__ B, int ldb,
               float* __restrict__ C, int ldc, int K) {
  __shared__ uint16_t As[BM * BK];
  __shared__ uint16_t Bs[BN * BK];
  const int tid = threadIdx.x, lane = tid & 63, wave = tid >> 6;
  const int lrow = lane & 15, quad = lane >> 4;
  const int wm = (wave >> 1) * 64, wn = (wave & 1) * 64;
  const long tm = blockIdx.x, tn = blockIdx.y;
  f32x4 acc[4][4] = {};
  const int srow = lane >> 2, scol = (lane & 3) * 8;
  for (int k0 = 0; k0 < K; k0 += BK) {
#pragma unroll
    for (int i = 0; i < 2; ++i) {
      int row = i * 64 + wave * 16 + srow;
      const uint16_t* gp = A + (tm * BM + row) * (long)lda + k0 + scol;
      __builtin_amdgcn_global_load_lds((gbl_void_t*)(uintptr_t)gp,
          (lds_void_t*)&As[i * 2048 + wave * 512], 16, 0, 0);
    }
#pragma unroll
    for (int i = 0; i < 2; ++i) {
      int row = i * 64 + wave * 16 + srow;
      const uint16_t* gp = B + (tn * BN + row) * (long)ldb + k0 + scol;
      __builtin_amdgcn_global_load_lds((gbl_void_t*)(uintptr_t)gp,
          (lds_void_t*)&Bs[i * 2048 + wave * 512], 16, 0, 0);
    }
    __syncthreads();
    bf16x8 a[4], b[4];
#pragma unroll
    for (int f = 0; f < 4; ++f)
      a[f] = *(const bf16x8*)&As[(wm + f * 16 + lrow) * BK + quad * 8];
#pragma unroll
    for (int f = 0; f < 4; ++f)
      b[f] = *(const bf16x8*)&Bs[(wn + f * 16 + lrow) * BK + quad * 8];
#pragma unroll
    for (int fm = 0; fm < 4; ++fm)
#pragma unroll
      for (int fn = 0; fn < 4; ++fn)
        acc[fm][fn] = __builtin_amdgcn_mfma_f32_16x16x32_bf16(
            a[fm], b[fn], acc[fm][fn], 0, 0, 0);
    __syncthreads();
  }
#pragma unroll
  for (int fm = 0; fm < 4; ++fm)
#pragma unroll
    for (int fn = 0; fn < 4; ++fn) {
      long col  = tn * BN + wn + fn * 16 + lrow;
      long row0 = tm * BM + wm + fm * 16 + quad * 4;
#pragma unroll
      for (int r = 0; r < 4; ++r)
        C[(row0 + r) * (long)ldc + col] = acc[fm][fn][r];
    }
}

// ---- fused level kernel ----------------------------------------------------
// A [M,K] bf16 (M mult of 128); Wg = [Wi;Wo;Wu] rows g*512+h, ld 1024.
// Tile: 128 rows x 64 cols per gate; waves 2x2 (64x32 each); 3 acc sets.
// Epilogue: c = sig(i)*tanh(u) [+ Fpart], Cbf=bf16(c), h=sig(o)*tanh(c);
// hsum over each parent's 16 children (16x16 frag + shfl quads) -> xh_next,
// plus x-half copy for the next level.
template <bool HAS_F>
__global__ __launch_bounds__(256)
void k_level(const uint16_t* __restrict__ A, int lda, int K,
             const uint16_t* __restrict__ Wg,
             const float* __restrict__ bi, const float* __restrict__ bo,
             const float* __restrict__ bu,
             const float* __restrict__ Fpart,     // [M,512] node-indexed
             uint16_t* __restrict__ Cbf,          // [M,512]
             const uint16_t* __restrict__ Xnext,  // [M/16,512] bf16
             uint16_t* __restrict__ xh_next) {    // [M/16,1024]
  __shared__ uint16_t As[128 * 32];      // 8 KB
  __shared__ uint16_t Bs[3 * 64 * 32];   // 12 KB
  const int tid = threadIdx.x, lane = tid & 63, wave = tid >> 6;
  const int lrow = lane & 15, quad = lane >> 4;
  const int wm = (wave >> 1) * 64, wn = (wave & 1) * 32;
  const long tm = blockIdx.x, tn = blockIdx.y;   // tn 0..7

  f32x4 acc[3][4][2] = {};
  const int srow = lane >> 2, scol = (lane & 3) * 8;

  for (int k0 = 0; k0 < K; k0 += 32) {
#pragma unroll
    for (int i = 0; i < 2; ++i) {        // A: 128x32
      int row = i * 64 + wave * 16 + srow;
      const uint16_t* gp = A + (tm * 128 + row) * (long)lda + k0 + scol;
      __builtin_amdgcn_global_load_lds((gbl_void_t*)(uintptr_t)gp,
          (lds_void_t*)&As[i * 2048 + wave * 512], 16, 0, 0);
    }
#pragma unroll
    for (int g = 0; g < 3; ++g) {        // B: 3 x (64x32)
      long grow = g * 512 + tn * 64 + wave * 16 + srow;
      const uint16_t* gp = Wg + grow * 1024 + k0 + scol;
      __builtin_amdgcn_global_load_lds((gbl_void_t*)(uintptr_t)gp,
          (lds_void_t*)&Bs[g * 2048 + wave * 512], 16, 0, 0);
    }
    __syncthreads();

    bf16x8 a[4], b[3][2];
#pragma unroll
    for (int f = 0; f < 4; ++f)
      a[f] = *(const bf16x8*)&As[(wm + f * 16 + lrow) * 32 + quad * 8];
#pragma unroll
    for (int g = 0; g < 3; ++g)
#pragma unroll
      for (int f = 0; f < 2; ++f)
        b[g][f] = *(const bf16x8*)&Bs[g * 2048 + (wn + f * 16 + lrow) * 32 +
                                      quad * 8];
#pragma unroll
    for (int g = 0; g < 3; ++g)
#pragma unroll
      for (int fm = 0; fm < 4; ++fm)
#pragma unroll
        for (int fn = 0; fn < 2; ++fn)
          acc[g][fm][fn] = __builtin_amdgcn_mfma_f32_16x16x32_bf16(
              a[fm], b[g][fn], acc[g][fm][fn], 0, 0, 0);
    __syncthreads();
  }

  // epilogue — C/D layout: col = lane&15, row = quad*4 + r  [HW-verified]
#pragma unroll
  for (int fn = 0; fn < 2; ++fn) {
    long col = tn * 64 + wn + fn * 16 + lrow;
    float biv = bi[col], bov = bo[col], buv = bu[col];
#pragma unroll
    for (int fm = 0; fm < 4; ++fm) {
      long row0 = tm * 128 + wm + fm * 16 + quad * 4;
      long pg   = tm * 8 + (wm >> 4) + fm;
      float hs = 0.f;
#pragma unroll
      for (int r = 0; r < 4; ++r) {
        long row = row0 + r;
        float iv = sig_(acc[0][fm][fn][r] + biv);
        float ov = sig_(acc[1][fm][fn][r] + bov);
        float uv = tanh_(acc[2][fm][fn][r] + buv);
        float c  = iv * uv;
        if (HAS_F) c += Fpart[row * 512 + col];
        Cbf[row * 512 + col] = f2bf(c);
        hs += ov * tanh_(c);
      }
      hs += __shfl_xor(hs, 16, 64);
      hs += __shfl_xor(hs, 32, 64);
      if (quad == 0) {
        xh_next[pg * 1024 + col]       = Xnext[pg * 512 + col];
        xh_next[pg * 1024 + 512 + col] = f2bf(hs);
      }
    }
  }
}

// ---- fc GEMM + fused forget-combine (round-4 verified) ---------------------
__global__ __launch_bounds__(256)
void k_fc_combine(const uint16_t* __restrict__ Cbf,
                  const uint16_t* __restrict__ Wfc, int ldb,
                  const float* __restrict__ Fx,
                  const float* __restrict__ bfb,
                  float* __restrict__ Fpart) {
  __shared__ uint16_t As[BM * BK];
  __shared__ uint16_t Bs[BN * BK];
  const int tid = threadIdx.x, lane = tid & 63, wave = tid >> 6;
  const int lrow = lane & 15, quad = lane >> 4;
  const int wm = (wave >> 1) * 64, wn = (wave & 1) * 64;
  const long tm = blockIdx.x, tn = blockIdx.y;
  const int K = 512, lda = 512;
  f32x4 acc[4][4] = {};
  const int srow = lane >> 2, scol = (lane & 3) * 8;
  for (int k0 = 0; k0 < K; k0 += BK) {
#pragma unroll
    for (int i = 0; i < 2; ++i) {
      int row = i * 64 + wave * 16 + srow;
      const uint16_t* gp = Cbf + (tm * BM + row) * (long)lda + k0 + scol;
      __builtin_amdgcn_global_load_lds((gbl_void_t*)(uintptr_t)gp,
          (lds_void_t*)&As[i * 2048 + wave * 512], 16, 0, 0);
    }
#pragma unroll
    for (int i = 0; i < 2; ++i) {
      int row = i * 64 + wave * 16 + srow;
      const uint16_t* gp = Wfc + (tn * BN + row) * (long)ldb + k0 + scol;
      __builtin_amdgcn_global_load_lds((gbl_void_t*)(uintptr_t)gp,
          (lds_void_t*)&Bs[i * 2048 + wave * 512], 16, 0, 0);
    }
    __syncthreads();
    bf16x8 a[4], b[4];
#pragma unroll
    for (int f = 0; f < 4; ++f)
      a[f] = *(const bf16x8*)&As[(wm + f * 16 + lrow) * BK + quad * 8];
#pragma unroll
    for (int f = 0; f < 4; ++f)
      b[f] = *(const bf16x8*)&Bs[(wn + f * 16 + lrow) * BK + quad * 8];
#pragma unroll
    for (int fm = 0; fm < 4; ++fm)
#pragma unroll
      for (int fn = 0; fn < 4; ++fn)
        acc[fm][fn] = __builtin_amdgcn_mfma_f32_16x16x32_bf16(
            a[fm], b[fn], acc[fm][fn], 0, 0, 0);
    __syncthreads();
  }
#pragma unroll
  for (int fm = 0; fm < 4; ++fm) {
    long pg   = tm * 8 + (wm >> 4) + fm;
    long row0 = tm * BM + wm + fm * 16 + quad * 4;
#pragma unroll
    for (int fn = 0; fn < 4; ++fn) {
      long col = tn * BN + wn + fn * 16 + lrow;
      float fx = Fx[pg * 512 + col] + bfb[col];
      float t = 0.f;
#pragma unroll
      for (int r = 0; r < 4; ++r)
        t += sig_(fx + acc[fm][fn][r]) * bf2f(Cbf[(row0 + r) * 512 + col]);
      t += __shfl_xor(t, 16, 64);
      t += __shfl_xor(t, 32, 64);
      if (quad == 0) Fpart[pg * 512 + col] = t;
    }
  }
}

// ---- wave-per-dot kernels (tiny levels) ------------------------------------
__global__ void k_dot_bb(const uint16_t* __restrict__ A, int lda,
                         const uint16_t* __restrict__ B, int ldb,
                         float* __restrict__ C, int ldc,
                         int M, int N, int K) {
  int wid  = (int)((blockIdx.x * (long)blockDim.x + threadIdx.x) >> 6);
  int lane = threadIdx.x & 63;
  if (wid >= M * N) return;
  int m = wid / N, n = wid - m * N;
  const uint16_t* a = A + (long)m * lda;
  const uint16_t* b = B + (long)n * ldb;
  int per = K >> 6, k0 = lane * per;
  float s = 0.f;
  for (int j = 0; j < per; j += 4) {
    ushort4 av = *(const ushort4*)(a + k0 + j);
    ushort4 bv = *(const ushort4*)(b + k0 + j);
    s += bf2f(av.x) * bf2f(bv.x) + bf2f(av.y) * bf2f(bv.y)
       + bf2f(av.z) * bf2f(bv.z) + bf2f(av.w) * bf2f(bv.w);
  }
#pragma unroll
  for (int off = 32; off; off >>= 1) s += __shfl_xor(s, off, 64);
  if (lane == 0) C[(long)m * ldc + n] = s;
}
__global__ void k_dot_f32(const float* __restrict__ A, int lda,
                          const float* __restrict__ B, int ldb,
                          float* __restrict__ C, int ldc,
                          int M, int N, int K) {
  int wid  = (int)((blockIdx.x * (long)blockDim.x + threadIdx.x) >> 6);
  int lane = threadIdx.x & 63;
  if (wid >= M * N) return;
  int m = wid / N, n = wid - m * N;
  const float* a = A + (long)m * lda;
  const float* b = B + (long)n * ldb;
  int per = K >> 6, k0 = lane * per;
  float s = 0.f;
  for (int j = 0; j < per; j += 4) {
    float4 av = *(const float4*)(a + k0 + j);
    float4 bv = *(const float4*)(b + k0 + j);
    s += av.x * bv.x + av.y * bv.y + av.z * bv.z + av.w * bv.w;
  }
#pragma unroll
  for (int off = 32; off; off >>= 1) s += __shfl_xor(s, off, 64);
  if (lane == 0) C[(long)m * ldc + n] = s;
}

// ---- upper-level h_sum + pack xh (children H fp32, x bf16) -----------------
__global__ void k_hsum_xh4(const float* __restrict__ Hc,
                           const uint16_t* __restrict__ xd,
                           uint16_t* __restrict__ xh, int n) {
  long idx = blockIdx.x * (long)blockDim.x + threadIdx.x;
  if (idx >= (long)n * 128) return;
  long p = idx >> 7; int hq = (int)(idx & 127) << 2;
  const float* hp = Hc + (p << 4) * 512 + hq;
  float4 s = {0.f, 0.f, 0.f, 0.f};
#pragma unroll
  for (int b = 0; b < 16; ++b) {
    float4 v = *(const float4*)(hp + b * 512);
    s.x += v.x; s.y += v.y; s.z += v.z; s.w += v.w;
  }
  *(ushort4*)(xh + p * 1024 + hq) = *(const ushort4*)(xd + p * 512 + hq);
  ushort4 hw = {f2bf(s.x), f2bf(s.y), f2bf(s.z), f2bf(s.w)};
  *(ushort4*)(xh + p * 1024 + 512 + hq) = hw;
}

// ---- separate combine (d=0 exact path) -------------------------------------
__global__ void k_combine4(const float* __restrict__ Fc,
                           const float* __restrict__ Fx,
                           const float* __restrict__ bfb,
                           const float* __restrict__ Cc,
                           float* __restrict__ Fpart, int nParents) {
  long idx = blockIdx.x * (long)blockDim.x + threadIdx.x;
  if (idx >= (long)nParents * 128) return;
  long pl = idx >> 7; int hq = (int)(idx & 127) << 2;
  float4 fxv = *(const float4*)(Fx + pl * 512 + hq);
  float4 bfv = *(const float4*)(bfb + hq);
  float fx0 = fxv.x + bfv.x, fx1 = fxv.y + bfv.y;
  float fx2 = fxv.z + bfv.z, fx3 = fxv.w + bfv.w;
  float a0 = 0.f, a1 = 0.f, a2 = 0.f, a3 = 0.f;
#pragma unroll 4
  for (int b = 0; b < 16; ++b) {
    long cl = pl * 16 + b;
    float4 f = *(const float4*)(Fc + cl * 512 + hq);
    float4 c = *(const float4*)(Cc + cl * 512 + hq);
    a0 += sig_(fx0 + f.x) * c.x;
    a1 += sig_(fx1 + f.y) * c.y;
    a2 += sig_(fx2 + f.z) * c.z;
    a3 += sig_(fx3 + f.w) * c.w;
  }
  float4 r = {a0, a1, a2, a3};
  *(float4*)(Fpart + pl * 512 + hq) = r;
}

// ---- final for tiny levels: C = i*u + Fpart, H = o*tanh(C) -----------------
__global__ void k_final4(const float* __restrict__ G,
                         const float* __restrict__ Fpart,
                         const float* __restrict__ bi,
                         const float* __restrict__ bo,
                         const float* __restrict__ bu,
                         float* __restrict__ H, float* __restrict__ Cv,
                         uint16_t* __restrict__ Cbf, int n) {
  long idx = blockIdx.x * (long)blockDim.x + threadIdx.x;
  if (idx >= (long)n * 128) return;
  long p = idx >> 7; int hq = (int)(idx & 127) << 2;
  const float* g = G + p * 1536;
  float4 gi = *(const float4*)(g + hq);
  float4 go = *(const float4*)(g + 512 + hq);
  float4 gu = *(const float4*)(g + 1024 + hq);
  float4 b_i = *(const float4*)(bi + hq);
  float4 b_o = *(const float4*)(bo + hq);
  float4 b_u = *(const float4*)(bu + hq);
  float4 fp = *(const float4*)(Fpart + p * 512 + hq);
  const float* gip = &gi.x; const float* gop = &go.x; const float* gup = &gu.x;
  const float* bip = &b_i.x; const float* bop = &b_o.x; const float* bup = &b_u.x;
  const float* fpp = &fp.x;
  float4 hv, cv;
  float* hvp = &hv.x; float* cvp = &cv.x;
  ushort4 cw; unsigned short* cwp = &cw.x;
#pragma unroll
  for (int j = 0; j < 4; ++j) {
    float iv = sig_(gip[j] + bip[j]);
    float ov = sig_(gop[j] + bop[j]);
    float uv = tanh_(gup[j] + bup[j]);
    float c  = iv * uv + fpp[j];
    cvp[j] = c;
    cwp[j] = f2bf(c);
    hvp[j] = ov * tanh_(c);
  }
  *(float4*)(H  + p * 512 + hq) = hv;
  *(float4*)(Cv + p * 512 + hq) = cv;
  *(ushort4*)(Cbf + p * 512 + hq) = cw;
}

// ---------------------------------------------------------------------------
extern "C" void kernel_launch(void* const* d_in, const int* in_sizes, int n_in,
                              void* d_out, int out_size, void* d_ws, size_t ws_size,
                              hipStream_t stream) {
  const float* x    = (const float*)d_in[0];
  const float* wi_w = (const float*)d_in[1];
  const float* wi_b = (const float*)d_in[2];
  const float* wf_w = (const float*)d_in[3];
  const float* wf_b = (const float*)d_in[4];
  const float* wo_w = (const float*)d_in[5];
  const float* wo_b = (const float*)d_in[6];
  const float* wu_w = (const float*)d_in[7];
  const float* wu_b = (const float*)d_in[8];
  (void)in_sizes; (void)n_in; (void)out_size; (void)ws_size;

  static const long offs[5] = {0, 1, 17, 273, 4369};
  const long NTOT = 69905;

  // ---- workspace (~175 MB of ~573 MB) ----
  char* ws = (char*)d_ws;
  size_t off = 0;
  auto alloc = [&](size_t bytes) -> void* {
    void* p = ws + off;
    off += (bytes + 255) & ~(size_t)255;
    return p;
  };
  uint16_t* Xbf   = (uint16_t*)alloc(NTOT * 512 * 2);            // 71.6 MB
  uint16_t* Wgw   = (uint16_t*)alloc((size_t)2048 * 1024 * 2);   // 4.2 MB
  uint16_t* Wg    = Wgw;                    // [Wi;Wo;Wu] rows 0..1535
  uint16_t* Wf    = Wgw + (size_t)1536 * 1024;  // rows 0..511
  float*    FxAll = (float*)alloc((size_t)4480 * 512 * 4);       // 9.2 MB
  uint16_t* Cbf   = (uint16_t*)alloc((size_t)65536 * 512 * 2);   // 67.1 MB
  uint16_t* CbfU  = (uint16_t*)alloc((size_t)4096 * 512 * 2);    // 4.2 MB
  uint16_t* CbfU2 = (uint16_t*)alloc((size_t)256 * 512 * 2);     // 0.26 MB
  uint16_t* xhA   = (uint16_t*)alloc((size_t)4096 * 1024 * 2);   // 8.4 MB
  uint16_t* xhB   = (uint16_t*)alloc((size_t)256 * 1024 * 2);    // 0.52 MB
  uint16_t* xhC   = (uint16_t*)alloc((size_t)16 * 1024 * 2);     // 32 KB
  float*    Fpart = (float*)alloc((size_t)4096 * 512 * 4);       // 8.4 MB
  float*    Gf    = (float*)alloc((size_t)16 * 1536 * 4);        // 98 KB
  float*    Fc    = (float*)alloc((size_t)16 * 512 * 4);
  float*    HupA  = (float*)alloc((size_t)16 * 512 * 4);
  float*    CupA  = (float*)alloc((size_t)16 * 512 * 4);

  auto blks = [](long n) { return (int)((n + 255) / 256); };

  // ---- converts (2 launches) ----
  {
    long n4 = NTOT * 512 / 4;
    k_conv_x<<<8192, 256, 0, stream>>>((const float4*)x, (ushort4*)Xbf, n4);
    k_conv_w<<<2048, 256, 0, stream>>>((const float4*)wi_w, (const float4*)wo_w,
                                       (const float4*)wu_w, (const float4*)wf_w,
                                       (ushort4*)Wgw);
  }

  // ---- Fx for ALL upper levels in one GEMM (node ids 0..4368, pad to 4480) --
  {
    dim3 grid(35, 4);
    k_gemm_bt<<<grid, 256, 0, stream>>>(Xbf, 512, Wf, 1024, FxAll, 512, 512);
  }

  // ---- leaf level: fused gates+LSTM+hsum (M=65536, K=512) ----
  {
    dim3 grid(512, 8);
    k_level<false><<<grid, 256, 0, stream>>>(
        Xbf + offs[4] * 512, 512, 512, Wg, wi_b, wo_b, wu_b, nullptr,
        Cbf, Xbf + offs[3] * 512, xhA);
  }
  { dim3 grid(512, 4);
    k_fc_combine<<<grid, 256, 0, stream>>>(Cbf, Wf + 512, 1024,
                                           FxAll + offs[3] * 512, wf_b, Fpart); }

  // ---- level 3 (M=4096, K=1024) ----
  { dim3 grid(32, 8);
    k_level<true><<<grid, 256, 0, stream>>>(
        xhA, 1024, 1024, Wg, wi_b, wo_b, wu_b, Fpart,
        CbfU, Xbf + offs[2] * 512, xhB); }
  { dim3 grid(32, 4);
    k_fc_combine<<<grid, 256, 0, stream>>>(CbfU, Wf + 512, 1024,
                                           FxAll + offs[2] * 512, wf_b, Fpart); }

  // ---- level 2 (M=256, K=1024) ----
  { dim3 grid(2, 8);
    k_level<true><<<grid, 256, 0, stream>>>(
        xhB, 1024, 1024, Wg, wi_b, wo_b, wu_b, Fpart,
        CbfU2, Xbf + offs[1] * 512, xhC); }
  { dim3 grid(2, 4);
    k_fc_combine<<<grid, 256, 0, stream>>>(CbfU2, Wf + 512, 1024,
                                           FxAll + offs[1] * 512, wf_b, Fpart); }

  // ---- level 1 (n=16): dots + final (keeps fp32 C for exact d=0 path) ----
  {
    long waves = 16L * 1536;
    k_dot_bb<<<(int)((waves * 64 + 255) / 256), 256, 0, stream>>>(
        xhC, 1024, Wg, 1024, Gf, 1536, 16, 1536, 1024);
    k_final4<<<blks(16L * 128), 256, 0, stream>>>(
        Gf, Fpart, wi_b, wo_b, wu_b, HupA, CupA, CbfU2, 16);
  }

  // ---- level 0 (root) ----
  k_hsum_xh4<<<1, 256, 0, stream>>>(HupA, Xbf + offs[0] * 512, xhC, 1);
  {
    long waves = 1536;
    k_dot_bb<<<(int)((waves * 64 + 255) / 256), 256, 0, stream>>>(
        xhC, 1024, Wg, 1024, Gf, 1536, 1, 1536, 1024);
  }
  {
    long waves = 16L * 512;
    k_dot_f32<<<(int)((waves * 64 + 255) / 256), 256, 0, stream>>>(
        CupA, 512, wf_w + 512, 1024, Fc, 512, 16, 512, 512);
  }
  k_combine4<<<1, 256, 0, stream>>>(Fc, FxAll, wf_b, CupA, Fpart, 1);
  k_final4<<<1, 256, 0, stream>>>(
      Gf, Fpart, wi_b, wo_b, wu_b,
      (float*)d_out, (float*)d_out + 512, CbfU2, 1);
}

// Round 6
// 614.112 us; speedup vs baseline: 2.3418x; 1.1100x over previous
//
#include <hip/hip_runtime.h>
#include <stdint.h>
#include <stddef.h>

// ---------------------------------------------------------------------------
// CSTreeLSTM on gfx950. Levels 1,16,256,4096,65536 (x offsets 0,1,17,273,4369).
// Round 6: k_level register diet (b-frags per-gate, launch_bounds(256,3) ->
// 3 waves/SIMD) + grid transpose (tn fastest) for L2-resident A panels.
// ---------------------------------------------------------------------------

typedef __bf16 bf16x8 __attribute__((ext_vector_type(8)));
typedef float  f32x4  __attribute__((ext_vector_type(4)));
typedef void __attribute__((address_space(3))) lds_void_t;
typedef void __attribute__((address_space(1))) gbl_void_t;

__device__ __forceinline__ uint16_t f2bf(float f) {
  union { float f; uint32_t u; } v; v.f = f;
  return (uint16_t)((v.u + 0x7fffu + ((v.u >> 16) & 1u)) >> 16);
}
__device__ __forceinline__ float bf2f(uint16_t u) {
  union { uint32_t u; float f; } v; v.u = (uint32_t)u << 16;
  return v.f;
}
__device__ __forceinline__ float sig_(float x) {
  return 1.0f / (1.0f + __expf(-x));
}
__device__ __forceinline__ float tanh_(float x) {
  x = fminf(15.f, fmaxf(-15.f, x));
  float e = __expf(2.f * x);
  return (e - 1.f) / (e + 1.f);
}

// ---- converts --------------------------------------------------------------
__global__ void k_conv_x(const float4* __restrict__ src,
                         ushort4* __restrict__ dst, long n4) {
  long i = blockIdx.x * (long)blockDim.x + threadIdx.x;
  long stride = (long)gridDim.x * blockDim.x;
  for (; i < n4; i += stride) {
    float4 v = src[i];
    ushort4 r;
    r.x = f2bf(v.x); r.y = f2bf(v.y); r.z = f2bf(v.z); r.w = f2bf(v.w);
    dst[i] = r;
  }
}
__global__ void k_conv_w(const float4* __restrict__ w0,
                         const float4* __restrict__ w1,
                         const float4* __restrict__ w2,
                         const float4* __restrict__ w3,
                         ushort4* __restrict__ dst) {
  const long per4 = (long)512 * 1024 / 4;
  long i = blockIdx.x * (long)blockDim.x + threadIdx.x;
  long stride = (long)gridDim.x * blockDim.x;
  for (; i < 4 * per4; i += stride) {
    long seg = i / per4, off2 = i - seg * per4;
    const float4* s = (seg == 0) ? w0 : (seg == 1) ? w1 : (seg == 2) ? w2 : w3;
    float4 v = s[off2];
    ushort4 r;
    r.x = f2bf(v.x); r.y = f2bf(v.y); r.z = f2bf(v.z); r.w = f2bf(v.w);
    dst[i] = r;
  }
}

#define BM 128
#define BN 128
#define BK 32

// ---- plain bf16 GEMM (FxAll only) ------------------------------------------
__global__ __launch_bounds__(256)
void k_gemm_bt(const uint16_t* __restrict__ A, int lda,
               const uint16_t* __restrict__ B, int ldb,
               float* __restrict__ C, int ldc, int K) {
  __shared__ uint16_t As[BM * BK];
  __shared__ uint16_t Bs[BN * BK];
  const int tid = threadIdx.x, lane = tid & 63, wave = tid >> 6;
  const int lrow = lane & 15, quad = lane >> 4;
  const int wm = (wave >> 1) * 64, wn = (wave & 1) * 64;
  const long tm = blockIdx.x, tn = blockIdx.y;
  f32x4 acc[4][4] = {};
  const int srow = lane >> 2, scol = (lane & 3) * 8;
  for (int k0 = 0; k0 < K; k0 += BK) {
#pragma unroll
    for (int i = 0; i < 2; ++i) {
      int row = i * 64 + wave * 16 + srow;
      const uint16_t* gp = A + (tm * BM + row) * (long)lda + k0 + scol;
      __builtin_amdgcn_global_load_lds((gbl_void_t*)(uintptr_t)gp,
          (lds_void_t*)&As[i * 2048 + wave * 512], 16, 0, 0);
    }
#pragma unroll
    for (int i = 0; i < 2; ++i) {
      int row = i * 64 + wave * 16 + srow;
      const uint16_t* gp = B + (tn * BN + row) * (long)ldb + k0 + scol;
      __builtin_amdgcn_global_load_lds((gbl_void_t*)(uintptr_t)gp,
          (lds_void_t*)&Bs[i * 2048 + wave * 512], 16, 0, 0);
    }
    __syncthreads();
    bf16x8 a[4], b[4];
#pragma unroll
    for (int f = 0; f < 4; ++f)
      a[f] = *(const bf16x8*)&As[(wm + f * 16 + lrow) * BK + quad * 8];
#pragma unroll
    for (int f = 0; f < 4; ++f)
      b[f] = *(const bf16x8*)&Bs[(wn + f * 16 + lrow) * BK + quad * 8];
#pragma unroll
    for (int fm = 0; fm < 4; ++fm)
#pragma unroll
      for (int fn = 0; fn < 4; ++fn)
        acc[fm][fn] = __builtin_amdgcn_mfma_f32_16x16x32_bf16(
            a[fm], b[fn], acc[fm][fn], 0, 0, 0);
    __syncthreads();
  }
#pragma unroll
  for (int fm = 0; fm < 4; ++fm)
#pragma unroll
    for (int fn = 0; fn < 4; ++fn) {
      long col  = tn * BN + wn + fn * 16 + lrow;
      long row0 = tm * BM + wm + fm * 16 + quad * 4;
#pragma unroll
      for (int r = 0; r < 4; ++r)
        C[(row0 + r) * (long)ldc + col] = acc[fm][fn][r];
    }
}

// ---- fused level kernel ----------------------------------------------------
// grid (8, M/128): tn = blockIdx.x (fast) so concurrent blocks share the A
// panel in L2. 3 acc sets (i,o,u); b-frags loaded per gate (reg diet);
// launch_bounds(256,3) targets 3 waves/SIMD (96 acc + ~70 arch VGPRs).
template <bool HAS_F>
__global__ __launch_bounds__(256, 3)
void k_level(const uint16_t* __restrict__ A, int lda, int K,
             const uint16_t* __restrict__ Wg,
             const float* __restrict__ bi, const float* __restrict__ bo,
             const float* __restrict__ bu,
             const float* __restrict__ Fpart,
             uint16_t* __restrict__ Cbf,
             const uint16_t* __restrict__ Xnext,
             uint16_t* __restrict__ xh_next) {
  __shared__ uint16_t As[128 * 32];
  __shared__ uint16_t Bs[3 * 64 * 32];
  const int tid = threadIdx.x, lane = tid & 63, wave = tid >> 6;
  const int lrow = lane & 15, quad = lane >> 4;
  const int wm = (wave >> 1) * 64, wn = (wave & 1) * 32;
  const long tn = blockIdx.x;      // 0..7  (fast: column strip)
  const long tm = blockIdx.y;      // row panel

  f32x4 acc[3][4][2] = {};
  const int srow = lane >> 2, scol = (lane & 3) * 8;

  for (int k0 = 0; k0 < K; k0 += 32) {
#pragma unroll
    for (int i = 0; i < 2; ++i) {
      int row = i * 64 + wave * 16 + srow;
      const uint16_t* gp = A + (tm * 128 + row) * (long)lda + k0 + scol;
      __builtin_amdgcn_global_load_lds((gbl_void_t*)(uintptr_t)gp,
          (lds_void_t*)&As[i * 2048 + wave * 512], 16, 0, 0);
    }
#pragma unroll
    for (int g = 0; g < 3; ++g) {
      long grow = g * 512 + tn * 64 + wave * 16 + srow;
      const uint16_t* gp = Wg + grow * 1024 + k0 + scol;
      __builtin_amdgcn_global_load_lds((gbl_void_t*)(uintptr_t)gp,
          (lds_void_t*)&Bs[g * 2048 + wave * 512], 16, 0, 0);
    }
    __syncthreads();

    bf16x8 a[4];
#pragma unroll
    for (int f = 0; f < 4; ++f)
      a[f] = *(const bf16x8*)&As[(wm + f * 16 + lrow) * 32 + quad * 8];
#pragma unroll
    for (int g = 0; g < 3; ++g) {
      bf16x8 b0 = *(const bf16x8*)&Bs[g * 2048 + (wn + lrow) * 32 + quad * 8];
      bf16x8 b1 = *(const bf16x8*)&Bs[g * 2048 + (wn + 16 + lrow) * 32 +
                                      quad * 8];
#pragma unroll
      for (int fm = 0; fm < 4; ++fm) {
        acc[g][fm][0] = __builtin_amdgcn_mfma_f32_16x16x32_bf16(
            a[fm], b0, acc[g][fm][0], 0, 0, 0);
        acc[g][fm][1] = __builtin_amdgcn_mfma_f32_16x16x32_bf16(
            a[fm], b1, acc[g][fm][1], 0, 0, 0);
      }
    }
    __syncthreads();
  }

  // epilogue — C/D layout: col = lane&15, row = quad*4 + r  [HW-verified]
#pragma unroll
  for (int fn = 0; fn < 2; ++fn) {
    long col = tn * 64 + wn + fn * 16 + lrow;
    float biv = bi[col], bov = bo[col], buv = bu[col];
#pragma unroll
    for (int fm = 0; fm < 4; ++fm) {
      long row0 = tm * 128 + wm + fm * 16 + quad * 4;
      long pg   = tm * 8 + (wm >> 4) + fm;
      float hs = 0.f;
#pragma unroll
      for (int r = 0; r < 4; ++r) {
        long row = row0 + r;
        float iv = sig_(acc[0][fm][fn][r] + biv);
        float ov = sig_(acc[1][fm][fn][r] + bov);
        float uv = tanh_(acc[2][fm][fn][r] + buv);
        float c  = iv * uv;
        if (HAS_F) c += Fpart[row * 512 + col];
        Cbf[row * 512 + col] = f2bf(c);
        hs += ov * tanh_(c);
      }
      hs += __shfl_xor(hs, 16, 64);
      hs += __shfl_xor(hs, 32, 64);
      if (quad == 0) {
        xh_next[pg * 1024 + col]       = Xnext[pg * 512 + col];
        xh_next[pg * 1024 + 512 + col] = f2bf(hs);
      }
    }
  }
}

// ---- fc GEMM + fused forget-combine ---------------------------------------
// grid (4, M/128): tn fast for L2 reuse of the Cbf panel.
__global__ __launch_bounds__(256, 3)
void k_fc_combine(const uint16_t* __restrict__ Cbf,
                  const uint16_t* __restrict__ Wfc, int ldb,
                  const float* __restrict__ Fx,
                  const float* __restrict__ bfb,
                  float* __restrict__ Fpart) {
  __shared__ uint16_t As[BM * BK];
  __shared__ uint16_t Bs[BN * BK];
  const int tid = threadIdx.x, lane = tid & 63, wave = tid >> 6;
  const int lrow = lane & 15, quad = lane >> 4;
  const int wm = (wave >> 1) * 64, wn = (wave & 1) * 64;
  const long tn = blockIdx.x;      // 0..3
  const long tm = blockIdx.y;
  const int K = 512, lda = 512;
  f32x4 acc[4][4] = {};
  const int srow = lane >> 2, scol = (lane & 3) * 8;
  for (int k0 = 0; k0 < K; k0 += BK) {
#pragma unroll
    for (int i = 0; i < 2; ++i) {
      int row = i * 64 + wave * 16 + srow;
      const uint16_t* gp = Cbf + (tm * BM + row) * (long)lda + k0 + scol;
      __builtin_amdgcn_global_load_lds((gbl_void_t*)(uintptr_t)gp,
          (lds_void_t*)&As[i * 2048 + wave * 512], 16, 0, 0);
    }
#pragma unroll
    for (int i = 0; i < 2; ++i) {
      int row = i * 64 + wave * 16 + srow;
      const uint16_t* gp = Wfc + (tn * BN + row) * (long)ldb + k0 + scol;
      __builtin_amdgcn_global_load_lds((gbl_void_t*)(uintptr_t)gp,
          (lds_void_t*)&Bs[i * 2048 + wave * 512], 16, 0, 0);
    }
    __syncthreads();
    bf16x8 a[4], b[4];
#pragma unroll
    for (int f = 0; f < 4; ++f)
      a[f] = *(const bf16x8*)&As[(wm + f * 16 + lrow) * BK + quad * 8];
#pragma unroll
    for (int f = 0; f < 4; ++f)
      b[f] = *(const bf16x8*)&Bs[(wn + f * 16 + lrow) * BK + quad * 8];
#pragma unroll
    for (int fm = 0; fm < 4; ++fm)
#pragma unroll
      for (int fn = 0; fn < 4; ++fn)
        acc[fm][fn] = __builtin_amdgcn_mfma_f32_16x16x32_bf16(
            a[fm], b[fn], acc[fm][fn], 0, 0, 0);
    __syncthreads();
  }
#pragma unroll
  for (int fm = 0; fm < 4; ++fm) {
    long pg   = tm * 8 + (wm >> 4) + fm;
    long row0 = tm * BM + wm + fm * 16 + quad * 4;
#pragma unroll
    for (int fn = 0; fn < 4; ++fn) {
      long col = tn * BN + wn + fn * 16 + lrow;
      float fx = Fx[pg * 512 + col] + bfb[col];
      float t = 0.f;
#pragma unroll
      for (int r = 0; r < 4; ++r)
        t += sig_(fx + acc[fm][fn][r]) * bf2f(Cbf[(row0 + r) * 512 + col]);
      t += __shfl_xor(t, 16, 64);
      t += __shfl_xor(t, 32, 64);
      if (quad == 0) Fpart[pg * 512 + col] = t;
    }
  }
}

// ---- wave-per-dot kernels (tiny levels) ------------------------------------
__global__ void k_dot_bb(const uint16_t* __restrict__ A, int lda,
                         const uint16_t* __restrict__ B, int ldb,
                         float* __restrict__ C, int ldc,
                         int M, int N, int K) {
  int wid  = (int)((blockIdx.x * (long)blockDim.x + threadIdx.x) >> 6);
  int lane = threadIdx.x & 63;
  if (wid >= M * N) return;
  int m = wid / N, n = wid - m * N;
  const uint16_t* a = A + (long)m * lda;
  const uint16_t* b = B + (long)n * ldb;
  int per = K >> 6, k0 = lane * per;
  float s = 0.f;
  for (int j = 0; j < per; j += 4) {
    ushort4 av = *(const ushort4*)(a + k0 + j);
    ushort4 bv = *(const ushort4*)(b + k0 + j);
    s += bf2f(av.x) * bf2f(bv.x) + bf2f(av.y) * bf2f(bv.y)
       + bf2f(av.z) * bf2f(bv.z) + bf2f(av.w) * bf2f(bv.w);
  }
#pragma unroll
  for (int off = 32; off; off >>= 1) s += __shfl_xor(s, off, 64);
  if (lane == 0) C[(long)m * ldc + n] = s;
}
__global__ void k_dot_f32(const float* __restrict__ A, int lda,
                          const float* __restrict__ B, int ldb,
                          float* __restrict__ C, int ldc,
                          int M, int N, int K) {
  int wid  = (int)((blockIdx.x * (long)blockDim.x + threadIdx.x) >> 6);
  int lane = threadIdx.x & 63;
  if (wid >= M * N) return;
  int m = wid / N, n = wid - m * N;
  const float* a = A + (long)m * lda;
  const float* b = B + (long)n * ldb;
  int per = K >> 6, k0 = lane * per;
  float s = 0.f;
  for (int j = 0; j < per; j += 4) {
    float4 av = *(const float4*)(a + k0 + j);
    float4 bv = *(const float4*)(b + k0 + j);
    s += av.x * bv.x + av.y * bv.y + av.z * bv.z + av.w * bv.w;
  }
#pragma unroll
  for (int off = 32; off; off >>= 1) s += __shfl_xor(s, off, 64);
  if (lane == 0) C[(long)m * ldc + n] = s;
}

// ---- upper-level h_sum + pack xh -------------------------------------------
__global__ void k_hsum_xh4(const float* __restrict__ Hc,
                           const uint16_t* __restrict__ xd,
                           uint16_t* __restrict__ xh, int n) {
  long idx = blockIdx.x * (long)blockDim.x + threadIdx.x;
  if (idx >= (long)n * 128) return;
  long p = idx >> 7; int hq = (int)(idx & 127) << 2;
  const float* hp = Hc + (p << 4) * 512 + hq;
  float4 s = {0.f, 0.f, 0.f, 0.f};
#pragma unroll
  for (int b = 0; b < 16; ++b) {
    float4 v = *(const float4*)(hp + b * 512);
    s.x += v.x; s.y += v.y; s.z += v.z; s.w += v.w;
  }
  *(ushort4*)(xh + p * 1024 + hq) = *(const ushort4*)(xd + p * 512 + hq);
  ushort4 hw = {f2bf(s.x), f2bf(s.y), f2bf(s.z), f2bf(s.w)};
  *(ushort4*)(xh + p * 1024 + 512 + hq) = hw;
}

// ---- separate combine (d=0 exact path) -------------------------------------
__global__ void k_combine4(const float* __restrict__ Fc,
                           const float* __restrict__ Fx,
                           const float* __restrict__ bfb,
                           const float* __restrict__ Cc,
                           float* __restrict__ Fpart, int nParents) {
  long idx = blockIdx.x * (long)blockDim.x + threadIdx.x;
  if (idx >= (long)nParents * 128) return;
  long pl = idx >> 7; int hq = (int)(idx & 127) << 2;
  float4 fxv = *(const float4*)(Fx + pl * 512 + hq);
  float4 bfv = *(const float4*)(bfb + hq);
  float fx0 = fxv.x + bfv.x, fx1 = fxv.y + bfv.y;
  float fx2 = fxv.z + bfv.z, fx3 = fxv.w + bfv.w;
  float a0 = 0.f, a1 = 0.f, a2 = 0.f, a3 = 0.f;
#pragma unroll 4
  for (int b = 0; b < 16; ++b) {
    long cl = pl * 16 + b;
    float4 f = *(const float4*)(Fc + cl * 512 + hq);
    float4 c = *(const float4*)(Cc + cl * 512 + hq);
    a0 += sig_(fx0 + f.x) * c.x;
    a1 += sig_(fx1 + f.y) * c.y;
    a2 += sig_(fx2 + f.z) * c.z;
    a3 += sig_(fx3 + f.w) * c.w;
  }
  float4 r = {a0, a1, a2, a3};
  *(float4*)(Fpart + pl * 512 + hq) = r;
}

// ---- final for tiny levels -------------------------------------------------
__global__ void k_final4(const float* __restrict__ G,
                         const float* __restrict__ Fpart,
                         const float* __restrict__ bi,
                         const float* __restrict__ bo,
                         const float* __restrict__ bu,
                         float* __restrict__ H, float* __restrict__ Cv,
                         uint16_t* __restrict__ Cbf, int n) {
  long idx = blockIdx.x * (long)blockDim.x + threadIdx.x;
  if (idx >= (long)n * 128) return;
  long p = idx >> 7; int hq = (int)(idx & 127) << 2;
  const float* g = G + p * 1536;
  float4 gi = *(const float4*)(g + hq);
  float4 go = *(const float4*)(g + 512 + hq);
  float4 gu = *(const float4*)(g + 1024 + hq);
  float4 b_i = *(const float4*)(bi + hq);
  float4 b_o = *(const float4*)(bo + hq);
  float4 b_u = *(const float4*)(bu + hq);
  float4 fp = *(const float4*)(Fpart + p * 512 + hq);
  const float* gip = &gi.x; const float* gop = &go.x; const float* gup = &gu.x;
  const float* bip = &b_i.x; const float* bop = &b_o.x; const float* bup = &b_u.x;
  const float* fpp = &fp.x;
  float4 hv, cv;
  float* hvp = &hv.x; float* cvp = &cv.x;
  ushort4 cw; unsigned short* cwp = &cw.x;
#pragma unroll
  for (int j = 0; j < 4; ++j) {
    float iv = sig_(gip[j] + bip[j]);
    float ov = sig_(gop[j] + bop[j]);
    float uv = tanh_(gup[j] + bup[j]);
    float c  = iv * uv + fpp[j];
    cvp[j] = c;
    cwp[j] = f2bf(c);
    hvp[j] = ov * tanh_(c);
  }
  *(float4*)(H  + p * 512 + hq) = hv;
  *(float4*)(Cv + p * 512 + hq) = cv;
  *(ushort4*)(Cbf + p * 512 + hq) = cw;
}

// ---------------------------------------------------------------------------
extern "C" void kernel_launch(void* const* d_in, const int* in_sizes, int n_in,
                              void* d_out, int out_size, void* d_ws, size_t ws_size,
                              hipStream_t stream) {
  const float* x    = (const float*)d_in[0];
  const float* wi_w = (const float*)d_in[1];
  const float* wi_b = (const float*)d_in[2];
  const float* wf_w = (const float*)d_in[3];
  const float* wf_b = (const float*)d_in[4];
  const float* wo_w = (const float*)d_in[5];
  const float* wo_b = (const float*)d_in[6];
  const float* wu_w = (const float*)d_in[7];
  const float* wu_b = (const float*)d_in[8];
  (void)in_sizes; (void)n_in; (void)out_size; (void)ws_size;

  static const long offs[5] = {0, 1, 17, 273, 4369};
  const long NTOT = 69905;

  // ---- workspace (~175 MB of ~573 MB) ----
  char* ws = (char*)d_ws;
  size_t off = 0;
  auto alloc = [&](size_t bytes) -> void* {
    void* p = ws + off;
    off += (bytes + 255) & ~(size_t)255;
    return p;
  };
  uint16_t* Xbf   = (uint16_t*)alloc(NTOT * 512 * 2);
  uint16_t* Wgw   = (uint16_t*)alloc((size_t)2048 * 1024 * 2);
  uint16_t* Wg    = Wgw;
  uint16_t* Wf    = Wgw + (size_t)1536 * 1024;
  float*    FxAll = (float*)alloc((size_t)4480 * 512 * 4);
  uint16_t* Cbf   = (uint16_t*)alloc((size_t)65536 * 512 * 2);
  uint16_t* CbfU  = (uint16_t*)alloc((size_t)4096 * 512 * 2);
  uint16_t* CbfU2 = (uint16_t*)alloc((size_t)256 * 512 * 2);
  uint16_t* xhA   = (uint16_t*)alloc((size_t)4096 * 1024 * 2);
  uint16_t* xhB   = (uint16_t*)alloc((size_t)256 * 1024 * 2);
  uint16_t* xhC   = (uint16_t*)alloc((size_t)16 * 1024 * 2);
  float*    Fpart = (float*)alloc((size_t)4096 * 512 * 4);
  float*    Gf    = (float*)alloc((size_t)16 * 1536 * 4);
  float*    Fc    = (float*)alloc((size_t)16 * 512 * 4);
  float*    HupA  = (float*)alloc((size_t)16 * 512 * 4);
  float*    CupA  = (float*)alloc((size_t)16 * 512 * 4);

  auto blks = [](long n) { return (int)((n + 255) / 256); };

  // ---- converts ----
  {
    long n4 = NTOT * 512 / 4;
    k_conv_x<<<8192, 256, 0, stream>>>((const float4*)x, (ushort4*)Xbf, n4);
    k_conv_w<<<2048, 256, 0, stream>>>((const float4*)wi_w, (const float4*)wo_w,
                                       (const float4*)wu_w, (const float4*)wf_w,
                                       (ushort4*)Wgw);
  }

  // ---- Fx for all upper levels (node ids 0..4368, pad to 4480) ----
  {
    dim3 grid(35, 4);
    k_gemm_bt<<<grid, 256, 0, stream>>>(Xbf, 512, Wf, 1024, FxAll, 512, 512);
  }

  // ---- leaf level (M=65536, K=512) ----
  {
    dim3 grid(8, 512);   // tn fast
    k_level<false><<<grid, 256, 0, stream>>>(
        Xbf + offs[4] * 512, 512, 512, Wg, wi_b, wo_b, wu_b, nullptr,
        Cbf, Xbf + offs[3] * 512, xhA);
  }
  { dim3 grid(4, 512);
    k_fc_combine<<<grid, 256, 0, stream>>>(Cbf, Wf + 512, 1024,
                                           FxAll + offs[3] * 512, wf_b, Fpart); }

  // ---- level 3 (M=4096, K=1024) ----
  { dim3 grid(8, 32);
    k_level<true><<<grid, 256, 0, stream>>>(
        xhA, 1024, 1024, Wg, wi_b, wo_b, wu_b, Fpart,
        CbfU, Xbf + offs[2] * 512, xhB); }
  { dim3 grid(4, 32);
    k_fc_combine<<<grid, 256, 0, stream>>>(CbfU, Wf + 512, 1024,
                                           FxAll + offs[2] * 512, wf_b, Fpart); }

  // ---- level 2 (M=256, K=1024) ----
  { dim3 grid(8, 2);
    k_level<true><<<grid, 256, 0, stream>>>(
        xhB, 1024, 1024, Wg, wi_b, wo_b, wu_b, Fpart,
        CbfU2, Xbf + offs[1] * 512, xhC); }
  { dim3 grid(4, 2);
    k_fc_combine<<<grid, 256, 0, stream>>>(CbfU2, Wf + 512, 1024,
                                           FxAll + offs[1] * 512, wf_b, Fpart); }

  // ---- level 1 (n=16) ----
  {
    long waves = 16L * 1536;
    k_dot_bb<<<(int)((waves * 64 + 255) / 256), 256, 0, stream>>>(
        xhC, 1024, Wg, 1024, Gf, 1536, 16, 1536, 1024);
    k_final4<<<blks(16L * 128), 256, 0, stream>>>(
        Gf, Fpart, wi_b, wo_b, wu_b, HupA, CupA, CbfU2, 16);
  }

  // ---- level 0 (root, exact fp32 fc path) ----
  k_hsum_xh4<<<1, 256, 0, stream>>>(HupA, Xbf + offs[0] * 512, xhC, 1);
  {
    long waves = 1536;
    k_dot_bb<<<(int)((waves * 64 + 255) / 256), 256, 0, stream>>>(
        xhC, 1024, Wg, 1024, Gf, 1536, 1, 1536, 1024);
  }
  {
    long waves = 16L * 512;
    k_dot_f32<<<(int)((waves * 64 + 255) / 256), 256, 0, stream>>>(
        CupA, 512, wf_w + 512, 1024, Fc, 512, 16, 512, 512);
  }
  k_combine4<<<1, 256, 0, stream>>>(Fc, FxAll, wf_b, CupA, Fpart, 1);
  k_final4<<<1, 256, 0, stream>>>(
      Gf, Fpart, wi_b, wo_b, wu_b,
      (float*)d_out, (float*)d_out + 512, CbfU2, 1);
}

// Round 7
// 600.464 us; speedup vs baseline: 2.3951x; 1.0227x over previous
//
#include <hip/hip_runtime.h>
#include <stdint.h>
#include <stddef.h>

// ---------------------------------------------------------------------------
// CSTreeLSTM on gfx950. Levels 1,16,256,4096,65536 (x offsets 0,1,17,273,4369).
// Round 7: XCD-aware block swizzle (b%8 -> XCD owns contiguous tm range, tn
// fastest within) so A panels are fetched once per XCD; BK=64 double-panel
// staging in k_level (half the barriers).
// ---------------------------------------------------------------------------

typedef __bf16 bf16x8 __attribute__((ext_vector_type(8)));
typedef float  f32x4  __attribute__((ext_vector_type(4)));
typedef void __attribute__((address_space(3))) lds_void_t;
typedef void __attribute__((address_space(1))) gbl_void_t;

__device__ __forceinline__ uint16_t f2bf(float f) {
  union { float f; uint32_t u; } v; v.f = f;
  return (uint16_t)((v.u + 0x7fffu + ((v.u >> 16) & 1u)) >> 16);
}
__device__ __forceinline__ float bf2f(uint16_t u) {
  union { uint32_t u; float f; } v; v.u = (uint32_t)u << 16;
  return v.f;
}
__device__ __forceinline__ float sig_(float x) {
  return 1.0f / (1.0f + __expf(-x));
}
__device__ __forceinline__ float tanh_(float x) {
  x = fminf(15.f, fmaxf(-15.f, x));
  float e = __expf(2.f * x);
  return (e - 1.f) / (e + 1.f);
}

// ---- converts --------------------------------------------------------------
__global__ void k_conv_x(const float4* __restrict__ src,
                         ushort4* __restrict__ dst, long n4) {
  long i = blockIdx.x * (long)blockDim.x + threadIdx.x;
  long stride = (long)gridDim.x * blockDim.x;
  for (; i < n4; i += stride) {
    float4 v = src[i];
    ushort4 r;
    r.x = f2bf(v.x); r.y = f2bf(v.y); r.z = f2bf(v.z); r.w = f2bf(v.w);
    dst[i] = r;
  }
}
__global__ void k_conv_w(const float4* __restrict__ w0,
                         const float4* __restrict__ w1,
                         const float4* __restrict__ w2,
                         const float4* __restrict__ w3,
                         ushort4* __restrict__ dst) {
  const long per4 = (long)512 * 1024 / 4;
  long i = blockIdx.x * (long)blockDim.x + threadIdx.x;
  long stride = (long)gridDim.x * blockDim.x;
  for (; i < 4 * per4; i += stride) {
    long seg = i / per4, off2 = i - seg * per4;
    const float4* s = (seg == 0) ? w0 : (seg == 1) ? w1 : (seg == 2) ? w2 : w3;
    float4 v = s[off2];
    ushort4 r;
    r.x = f2bf(v.x); r.y = f2bf(v.y); r.z = f2bf(v.z); r.w = f2bf(v.w);
    dst[i] = r;
  }
}

#define BM 128
#define BN 128
#define BK 32

// ---- plain bf16 GEMM (FxAll only) ------------------------------------------
__global__ __launch_bounds__(256)
void k_gemm_bt(const uint16_t* __restrict__ A, int lda,
               const uint16_t* __restrict__ B, int ldb,
               float* __restrict__ C, int ldc, int K) {
  __shared__ uint16_t As[BM * BK];
  __shared__ uint16_t Bs[BN * BK];
  const int tid = threadIdx.x, lane = tid & 63, wave = tid >> 6;
  const int lrow = lane & 15, quad = lane >> 4;
  const int wm = (wave >> 1) * 64, wn = (wave & 1) * 64;
  const long tm = blockIdx.x, tn = blockIdx.y;
  f32x4 acc[4][4] = {};
  const int srow = lane >> 2, scol = (lane & 3) * 8;
  for (int k0 = 0; k0 < K; k0 += BK) {
#pragma unroll
    for (int i = 0; i < 2; ++i) {
      int row = i * 64 + wave * 16 + srow;
      const uint16_t* gp = A + (tm * BM + row) * (long)lda + k0 + scol;
      __builtin_amdgcn_global_load_lds((gbl_void_t*)(uintptr_t)gp,
          (lds_void_t*)&As[i * 2048 + wave * 512], 16, 0, 0);
    }
#pragma unroll
    for (int i = 0; i < 2; ++i) {
      int row = i * 64 + wave * 16 + srow;
      const uint16_t* gp = B + (tn * BN + row) * (long)ldb + k0 + scol;
      __builtin_amdgcn_global_load_lds((gbl_void_t*)(uintptr_t)gp,
          (lds_void_t*)&Bs[i * 2048 + wave * 512], 16, 0, 0);
    }
    __syncthreads();
    bf16x8 a[4], b[4];
#pragma unroll
    for (int f = 0; f < 4; ++f)
      a[f] = *(const bf16x8*)&As[(wm + f * 16 + lrow) * BK + quad * 8];
#pragma unroll
    for (int f = 0; f < 4; ++f)
      b[f] = *(const bf16x8*)&Bs[(wn + f * 16 + lrow) * BK + quad * 8];
#pragma unroll
    for (int fm = 0; fm < 4; ++fm)
#pragma unroll
      for (int fn = 0; fn < 4; ++fn)
        acc[fm][fn] = __builtin_amdgcn_mfma_f32_16x16x32_bf16(
            a[fm], b[fn], acc[fm][fn], 0, 0, 0);
    __syncthreads();
  }
#pragma unroll
  for (int fm = 0; fm < 4; ++fm)
#pragma unroll
    for (int fn = 0; fn < 4; ++fn) {
      long col  = tn * BN + wn + fn * 16 + lrow;
      long row0 = tm * BM + wm + fm * 16 + quad * 4;
#pragma unroll
      for (int r = 0; r < 4; ++r)
        C[(row0 + r) * (long)ldc + col] = acc[fm][fn][r];
    }
}

// ---- fused level kernel ----------------------------------------------------
// 1-D grid of nTm*8 blocks; XCD swizzle: x=b&7 (XCD), contiguous tm range per
// XCD, tn fastest. BK=64 as two 32-wide panels; one barrier pair per 64 K.
template <bool HAS_F>
__global__ __launch_bounds__(256, 3)
void k_level(const uint16_t* __restrict__ A, int lda, int K,
             const uint16_t* __restrict__ Wg,
             const float* __restrict__ bi, const float* __restrict__ bo,
             const float* __restrict__ bu,
             const float* __restrict__ Fpart,
             uint16_t* __restrict__ Cbf,
             const uint16_t* __restrict__ Xnext,
             uint16_t* __restrict__ xh_next) {
  __shared__ uint16_t As[2][128 * 32];      // 16 KB
  __shared__ uint16_t Bs[2][3 * 64 * 32];   // 24 KB
  const int tid = threadIdx.x, lane = tid & 63, wave = tid >> 6;
  const int lrow = lane & 15, quad = lane >> 4;
  const int wm = (wave >> 1) * 64, wn = (wave & 1) * 32;

  long tm, tn;
  {
    const int nTm = (int)(gridDim.x >> 3);
    int b = blockIdx.x;
    if ((nTm & 7) == 0) {           // XCD swizzle (dispatch round-robin mod 8)
      int x = b & 7, j = b >> 3, per = nTm >> 3;
      tn = j & 7; tm = (long)x * per + (j >> 3);
    } else { tm = b >> 3; tn = b & 7; }
  }

  f32x4 acc[3][4][2] = {};
  const int srow = lane >> 2, scol = (lane & 3) * 8;

  for (int k0 = 0; k0 < K; k0 += 64) {
#pragma unroll
    for (int h = 0; h < 2; ++h) {
      int kk = k0 + h * 32;
#pragma unroll
      for (int i = 0; i < 2; ++i) {
        int row = i * 64 + wave * 16 + srow;
        const uint16_t* gp = A + (tm * 128 + row) * (long)lda + kk + scol;
        __builtin_amdgcn_global_load_lds((gbl_void_t*)(uintptr_t)gp,
            (lds_void_t*)&As[h][i * 2048 + wave * 512], 16, 0, 0);
      }
#pragma unroll
      for (int g = 0; g < 3; ++g) {
        long grow = g * 512 + tn * 64 + wave * 16 + srow;
        const uint16_t* gp = Wg + grow * 1024 + kk + scol;
        __builtin_amdgcn_global_load_lds((gbl_void_t*)(uintptr_t)gp,
            (lds_void_t*)&Bs[h][g * 2048 + wave * 512], 16, 0, 0);
      }
    }
    __syncthreads();

#pragma unroll
    for (int h = 0; h < 2; ++h) {
      bf16x8 a[4];
#pragma unroll
      for (int f = 0; f < 4; ++f)
        a[f] = *(const bf16x8*)&As[h][(wm + f * 16 + lrow) * 32 + quad * 8];
#pragma unroll
      for (int g = 0; g < 3; ++g) {
        bf16x8 b0 = *(const bf16x8*)&Bs[h][g * 2048 + (wn + lrow) * 32 +
                                           quad * 8];
        bf16x8 b1 = *(const bf16x8*)&Bs[h][g * 2048 + (wn + 16 + lrow) * 32 +
                                           quad * 8];
#pragma unroll
        for (int fm = 0; fm < 4; ++fm) {
          acc[g][fm][0] = __builtin_amdgcn_mfma_f32_16x16x32_bf16(
              a[fm], b0, acc[g][fm][0], 0, 0, 0);
          acc[g][fm][1] = __builtin_amdgcn_mfma_f32_16x16x32_bf16(
              a[fm], b1, acc[g][fm][1], 0, 0, 0);
        }
      }
    }
    __syncthreads();
  }

  // epilogue — C/D layout: col = lane&15, row = quad*4 + r  [HW-verified]
#pragma unroll
  for (int fn = 0; fn < 2; ++fn) {
    long col = tn * 64 + wn + fn * 16 + lrow;
    float biv = bi[col], bov = bo[col], buv = bu[col];
#pragma unroll
    for (int fm = 0; fm < 4; ++fm) {
      long row0 = tm * 128 + wm + fm * 16 + quad * 4;
      long pg   = tm * 8 + (wm >> 4) + fm;
      float hs = 0.f;
#pragma unroll
      for (int r = 0; r < 4; ++r) {
        long row = row0 + r;
        float iv = sig_(acc[0][fm][fn][r] + biv);
        float ov = sig_(acc[1][fm][fn][r] + bov);
        float uv = tanh_(acc[2][fm][fn][r] + buv);
        float c  = iv * uv;
        if (HAS_F) c += Fpart[row * 512 + col];
        Cbf[row * 512 + col] = f2bf(c);
        hs += ov * tanh_(c);
      }
      hs += __shfl_xor(hs, 16, 64);
      hs += __shfl_xor(hs, 32, 64);
      if (quad == 0) {
        xh_next[pg * 1024 + col]       = Xnext[pg * 512 + col];
        xh_next[pg * 1024 + 512 + col] = f2bf(hs);
      }
    }
  }
}

// ---- fc GEMM + fused forget-combine (XCD-swizzled 1-D grid, nTm*4 blocks) --
__global__ __launch_bounds__(256, 3)
void k_fc_combine(const uint16_t* __restrict__ Cbf,
                  const uint16_t* __restrict__ Wfc, int ldb,
                  const float* __restrict__ Fx,
                  const float* __restrict__ bfb,
                  float* __restrict__ Fpart) {
  __shared__ uint16_t As[BM * BK];
  __shared__ uint16_t Bs[BN * BK];
  const int tid = threadIdx.x, lane = tid & 63, wave = tid >> 6;
  const int lrow = lane & 15, quad = lane >> 4;
  const int wm = (wave >> 1) * 64, wn = (wave & 1) * 64;
  long tm, tn;
  {
    const int nTm = (int)(gridDim.x >> 2);
    int b = blockIdx.x;
    if ((nTm & 7) == 0) {
      int x = b & 7, j = b >> 3, per = nTm >> 3;
      tn = j & 3; tm = (long)x * per + (j >> 2);
    } else { tm = b >> 2; tn = b & 3; }
  }
  const int K = 512, lda = 512;
  f32x4 acc[4][4] = {};
  const int srow = lane >> 2, scol = (lane & 3) * 8;
  for (int k0 = 0; k0 < K; k0 += BK) {
#pragma unroll
    for (int i = 0; i < 2; ++i) {
      int row = i * 64 + wave * 16 + srow;
      const uint16_t* gp = Cbf + (tm * BM + row) * (long)lda + k0 + scol;
      __builtin_amdgcn_global_load_lds((gbl_void_t*)(uintptr_t)gp,
          (lds_void_t*)&As[i * 2048 + wave * 512], 16, 0, 0);
    }
#pragma unroll
    for (int i = 0; i < 2; ++i) {
      int row = i * 64 + wave * 16 + srow;
      const uint16_t* gp = Wfc + (tn * BN + row) * (long)ldb + k0 + scol;
      __builtin_amdgcn_global_load_lds((gbl_void_t*)(uintptr_t)gp,
          (lds_void_t*)&Bs[i * 2048 + wave * 512], 16, 0, 0);
    }
    __syncthreads();
    bf16x8 a[4], b[4];
#pragma unroll
    for (int f = 0; f < 4; ++f)
      a[f] = *(const bf16x8*)&As[(wm + f * 16 + lrow) * BK + quad * 8];
#pragma unroll
    for (int f = 0; f < 4; ++f)
      b[f] = *(const bf16x8*)&Bs[(wn + f * 16 + lrow) * BK + quad * 8];
#pragma unroll
    for (int fm = 0; fm < 4; ++fm)
#pragma unroll
      for (int fn = 0; fn < 4; ++fn)
        acc[fm][fn] = __builtin_amdgcn_mfma_f32_16x16x32_bf16(
            a[fm], b[fn], acc[fm][fn], 0, 0, 0);
    __syncthreads();
  }
#pragma unroll
  for (int fm = 0; fm < 4; ++fm) {
    long pg   = tm * 8 + (wm >> 4) + fm;
    long row0 = tm * BM + wm + fm * 16 + quad * 4;
#pragma unroll
    for (int fn = 0; fn < 4; ++fn) {
      long col = tn * BN + wn + fn * 16 + lrow;
      float fx = Fx[pg * 512 + col] + bfb[col];
      float t = 0.f;
#pragma unroll
      for (int r = 0; r < 4; ++r)
        t += sig_(fx + acc[fm][fn][r]) * bf2f(Cbf[(row0 + r) * 512 + col]);
      t += __shfl_xor(t, 16, 64);
      t += __shfl_xor(t, 32, 64);
      if (quad == 0) Fpart[pg * 512 + col] = t;
    }
  }
}

// ---- wave-per-dot kernels (tiny levels) ------------------------------------
__global__ void k_dot_bb(const uint16_t* __restrict__ A, int lda,
                         const uint16_t* __restrict__ B, int ldb,
                         float* __restrict__ C, int ldc,
                         int M, int N, int K) {
  int wid  = (int)((blockIdx.x * (long)blockDim.x + threadIdx.x) >> 6);
  int lane = threadIdx.x & 63;
  if (wid >= M * N) return;
  int m = wid / N, n = wid - m * N;
  const uint16_t* a = A + (long)m * lda;
  const uint16_t* b = B + (long)n * ldb;
  int per = K >> 6, k0 = lane * per;
  float s = 0.f;
  for (int j = 0; j < per; j += 4) {
    ushort4 av = *(const ushort4*)(a + k0 + j);
    ushort4 bv = *(const ushort4*)(b + k0 + j);
    s += bf2f(av.x) * bf2f(bv.x) + bf2f(av.y) * bf2f(bv.y)
       + bf2f(av.z) * bf2f(bv.z) + bf2f(av.w) * bf2f(bv.w);
  }
#pragma unroll
  for (int off = 32; off; off >>= 1) s += __shfl_xor(s, off, 64);
  if (lane == 0) C[(long)m * ldc + n] = s;
}
__global__ void k_dot_f32(const float* __restrict__ A, int lda,
                          const float* __restrict__ B, int ldb,
                          float* __restrict__ C, int ldc,
                          int M, int N, int K) {
  int wid  = (int)((blockIdx.x * (long)blockDim.x + threadIdx.x) >> 6);
  int lane = threadIdx.x & 63;
  if (wid >= M * N) return;
  int m = wid / N, n = wid - m * N;
  const float* a = A + (long)m * lda;
  const float* b = B + (long)n * ldb;
  int per = K >> 6, k0 = lane * per;
  float s = 0.f;
  for (int j = 0; j < per; j += 4) {
    float4 av = *(const float4*)(a + k0 + j);
    float4 bv = *(const float4*)(b + k0 + j);
    s += av.x * bv.x + av.y * bv.y + av.z * bv.z + av.w * bv.w;
  }
#pragma unroll
  for (int off = 32; off; off >>= 1) s += __shfl_xor(s, off, 64);
  if (lane == 0) C[(long)m * ldc + n] = s;
}

// ---- upper-level h_sum + pack xh -------------------------------------------
__global__ void k_hsum_xh4(const float* __restrict__ Hc,
                           const uint16_t* __restrict__ xd,
                           uint16_t* __restrict__ xh, int n) {
  long idx = blockIdx.x * (long)blockDim.x + threadIdx.x;
  if (idx >= (long)n * 128) return;
  long p = idx >> 7; int hq = (int)(idx & 127) << 2;
  const float* hp = Hc + (p << 4) * 512 + hq;
  float4 s = {0.f, 0.f, 0.f, 0.f};
#pragma unroll
  for (int b = 0; b < 16; ++b) {
    float4 v = *(const float4*)(hp + b * 512);
    s.x += v.x; s.y += v.y; s.z += v.z; s.w += v.w;
  }
  *(ushort4*)(xh + p * 1024 + hq) = *(const ushort4*)(xd + p * 512 + hq);
  ushort4 hw = {f2bf(s.x), f2bf(s.y), f2bf(s.z), f2bf(s.w)};
  *(ushort4*)(xh + p * 1024 + 512 + hq) = hw;
}

// ---- separate combine (d=0 exact path) -------------------------------------
__global__ void k_combine4(const float* __restrict__ Fc,
                           const float* __restrict__ Fx,
                           const float* __restrict__ bfb,
                           const float* __restrict__ Cc,
                           float* __restrict__ Fpart, int nParents) {
  long idx = blockIdx.x * (long)blockDim.x + threadIdx.x;
  if (idx >= (long)nParents * 128) return;
  long pl = idx >> 7; int hq = (int)(idx & 127) << 2;
  float4 fxv = *(const float4*)(Fx + pl * 512 + hq);
  float4 bfv = *(const float4*)(bfb + hq);
  float fx0 = fxv.x + bfv.x, fx1 = fxv.y + bfv.y;
  float fx2 = fxv.z + bfv.z, fx3 = fxv.w + bfv.w;
  float a0 = 0.f, a1 = 0.f, a2 = 0.f, a3 = 0.f;
#pragma unroll 4
  for (int b = 0; b < 16; ++b) {
    long cl = pl * 16 + b;
    float4 f = *(const float4*)(Fc + cl * 512 + hq);
    float4 c = *(const float4*)(Cc + cl * 512 + hq);
    a0 += sig_(fx0 + f.x) * c.x;
    a1 += sig_(fx1 + f.y) * c.y;
    a2 += sig_(fx2 + f.z) * c.z;
    a3 += sig_(fx3 + f.w) * c.w;
  }
  float4 r = {a0, a1, a2, a3};
  *(float4*)(Fpart + pl * 512 + hq) = r;
}

// ---- final for tiny levels -------------------------------------------------
__global__ void k_final4(const float* __restrict__ G,
                         const float* __restrict__ Fpart,
                         const float* __restrict__ bi,
                         const float* __restrict__ bo,
                         const float* __restrict__ bu,
                         float* __restrict__ H, float* __restrict__ Cv,
                         uint16_t* __restrict__ Cbf, int n) {
  long idx = blockIdx.x * (long)blockDim.x + threadIdx.x;
  if (idx >= (long)n * 128) return;
  long p = idx >> 7; int hq = (int)(idx & 127) << 2;
  const float* g = G + p * 1536;
  float4 gi = *(const float4*)(g + hq);
  float4 go = *(const float4*)(g + 512 + hq);
  float4 gu = *(const float4*)(g + 1024 + hq);
  float4 b_i = *(const float4*)(bi + hq);
  float4 b_o = *(const float4*)(bo + hq);
  float4 b_u = *(const float4*)(bu + hq);
  float4 fp = *(const float4*)(Fpart + p * 512 + hq);
  const float* gip = &gi.x; const float* gop = &go.x; const float* gup = &gu.x;
  const float* bip = &b_i.x; const float* bop = &b_o.x; const float* bup = &b_u.x;
  const float* fpp = &fp.x;
  float4 hv, cv;
  float* hvp = &hv.x; float* cvp = &cv.x;
  ushort4 cw; unsigned short* cwp = &cw.x;
#pragma unroll
  for (int j = 0; j < 4; ++j) {
    float iv = sig_(gip[j] + bip[j]);
    float ov = sig_(gop[j] + bop[j]);
    float uv = tanh_(gup[j] + bup[j]);
    float c  = iv * uv + fpp[j];
    cvp[j] = c;
    cwp[j] = f2bf(c);
    hvp[j] = ov * tanh_(c);
  }
  *(float4*)(H  + p * 512 + hq) = hv;
  *(float4*)(Cv + p * 512 + hq) = cv;
  *(ushort4*)(Cbf + p * 512 + hq) = cw;
}

// ---------------------------------------------------------------------------
extern "C" void kernel_launch(void* const* d_in, const int* in_sizes, int n_in,
                              void* d_out, int out_size, void* d_ws, size_t ws_size,
                              hipStream_t stream) {
  const float* x    = (const float*)d_in[0];
  const float* wi_w = (const float*)d_in[1];
  const float* wi_b = (const float*)d_in[2];
  const float* wf_w = (const float*)d_in[3];
  const float* wf_b = (const float*)d_in[4];
  const float* wo_w = (const float*)d_in[5];
  const float* wo_b = (const float*)d_in[6];
  const float* wu_w = (const float*)d_in[7];
  const float* wu_b = (const float*)d_in[8];
  (void)in_sizes; (void)n_in; (void)out_size; (void)ws_size;

  static const long offs[5] = {0, 1, 17, 273, 4369};
  const long NTOT = 69905;

  // ---- workspace (~175 MB of ~573 MB) ----
  char* ws = (char*)d_ws;
  size_t off = 0;
  auto alloc = [&](size_t bytes) -> void* {
    void* p = ws + off;
    off += (bytes + 255) & ~(size_t)255;
    return p;
  };
  uint16_t* Xbf   = (uint16_t*)alloc(NTOT * 512 * 2);
  uint16_t* Wgw   = (uint16_t*)alloc((size_t)2048 * 1024 * 2);
  uint16_t* Wg    = Wgw;
  uint16_t* Wf    = Wgw + (size_t)1536 * 1024;
  float*    FxAll = (float*)alloc((size_t)4480 * 512 * 4);
  uint16_t* Cbf   = (uint16_t*)alloc((size_t)65536 * 512 * 2);
  uint16_t* CbfU  = (uint16_t*)alloc((size_t)4096 * 512 * 2);
  uint16_t* CbfU2 = (uint16_t*)alloc((size_t)256 * 512 * 2);
  uint16_t* xhA   = (uint16_t*)alloc((size_t)4096 * 1024 * 2);
  uint16_t* xhB   = (uint16_t*)alloc((size_t)256 * 1024 * 2);
  uint16_t* xhC   = (uint16_t*)alloc((size_t)16 * 1024 * 2);
  float*    Fpart = (float*)alloc((size_t)4096 * 512 * 4);
  float*    Gf    = (float*)alloc((size_t)16 * 1536 * 4);
  float*    Fc    = (float*)alloc((size_t)16 * 512 * 4);
  float*    HupA  = (float*)alloc((size_t)16 * 512 * 4);
  float*    CupA  = (float*)alloc((size_t)16 * 512 * 4);

  auto blks = [](long n) { return (int)((n + 255) / 256); };

  // ---- converts ----
  {
    long n4 = NTOT * 512 / 4;
    k_conv_x<<<8192, 256, 0, stream>>>((const float4*)x, (ushort4*)Xbf, n4);
    k_conv_w<<<2048, 256, 0, stream>>>((const float4*)wi_w, (const float4*)wo_w,
                                       (const float4*)wu_w, (const float4*)wf_w,
                                       (ushort4*)Wgw);
  }

  // ---- Fx for all upper levels (node ids 0..4368, pad to 4480) ----
  {
    dim3 grid(35, 4);
    k_gemm_bt<<<grid, 256, 0, stream>>>(Xbf, 512, Wf, 1024, FxAll, 512, 512);
  }

  // ---- leaf level (M=65536, K=512): nTm=512, 1-D swizzled grid ----
  k_level<false><<<4096, 256, 0, stream>>>(
      Xbf + offs[4] * 512, 512, 512, Wg, wi_b, wo_b, wu_b, nullptr,
      Cbf, Xbf + offs[3] * 512, xhA);
  k_fc_combine<<<2048, 256, 0, stream>>>(Cbf, Wf + 512, 1024,
                                         FxAll + offs[3] * 512, wf_b, Fpart);

  // ---- level 3 (M=4096, K=1024): nTm=32 ----
  k_level<true><<<256, 256, 0, stream>>>(
      xhA, 1024, 1024, Wg, wi_b, wo_b, wu_b, Fpart,
      CbfU, Xbf + offs[2] * 512, xhB);
  k_fc_combine<<<128, 256, 0, stream>>>(CbfU, Wf + 512, 1024,
                                        FxAll + offs[2] * 512, wf_b, Fpart);

  // ---- level 2 (M=256, K=1024): nTm=2 (plain mapping) ----
  k_level<true><<<16, 256, 0, stream>>>(
      xhB, 1024, 1024, Wg, wi_b, wo_b, wu_b, Fpart,
      CbfU2, Xbf + offs[1] * 512, xhC);
  k_fc_combine<<<8, 256, 0, stream>>>(CbfU2, Wf + 512, 1024,
                                      FxAll + offs[1] * 512, wf_b, Fpart);

  // ---- level 1 (n=16) ----
  {
    long waves = 16L * 1536;
    k_dot_bb<<<(int)((waves * 64 + 255) / 256), 256, 0, stream>>>(
        xhC, 1024, Wg, 1024, Gf, 1536, 16, 1536, 1024);
    k_final4<<<blks(16L * 128), 256, 0, stream>>>(
        Gf, Fpart, wi_b, wo_b, wu_b, HupA, CupA, CbfU2, 16);
  }

  // ---- level 0 (root, exact fp32 fc path) ----
  k_hsum_xh4<<<1, 256, 0, stream>>>(HupA, Xbf + offs[0] * 512, xhC, 1);
  {
    long waves = 1536;
    k_dot_bb<<<(int)((waves * 64 + 255) / 256), 256, 0, stream>>>(
        xhC, 1024, Wg, 1024, Gf, 1536, 1, 1536, 1024);
  }
  {
    long waves = 16L * 512;
    k_dot_f32<<<(int)((waves * 64 + 255) / 256), 256, 0, stream>>>(
        CupA, 512, wf_w + 512, 1024, Fc, 512, 16, 512, 512);
  }
  k_combine4<<<1, 256, 0, stream>>>(Fc, FxAll, wf_b, CupA, Fpart, 1);
  k_final4<<<1, 256, 0, stream>>>(
      Gf, Fpart, wi_b, wo_b, wu_b,
      (float*)d_out, (float*)d_out + 512, CbfU2, 1);
}

// Round 8
// 533.212 us; speedup vs baseline: 2.6971x; 1.1261x over previous
//
#include <hip/hip_runtime.h>
#include <stdint.h>
#include <stddef.h>

// ---------------------------------------------------------------------------
// CSTreeLSTM on gfx950. Levels 1,16,256,4096,65536 (x offsets 0,1,17,273,4369).
// Round 8: native-rcp transcendentals (v_rcp_f32, no Newton divide) in the
// GEMM epilogues; BK=64 double-panel staging in k_fc_combine. XCD swizzle
// (round 7, FETCH 268->43 MB) retained.
// ---------------------------------------------------------------------------

typedef __bf16 bf16x8 __attribute__((ext_vector_type(8)));
typedef float  f32x4  __attribute__((ext_vector_type(4)));
typedef void __attribute__((address_space(3))) lds_void_t;
typedef void __attribute__((address_space(1))) gbl_void_t;

__device__ __forceinline__ uint16_t f2bf(float f) {
  union { float f; uint32_t u; } v; v.f = f;
  return (uint16_t)((v.u + 0x7fffu + ((v.u >> 16) & 1u)) >> 16);
}
__device__ __forceinline__ float bf2f(uint16_t u) {
  union { uint32_t u; float f; } v; v.u = (uint32_t)u << 16;
  return v.f;
}
// native v_rcp_f32 (~1 ulp) -- threshold is 4.0, error budget is huge
__device__ __forceinline__ float sig_(float x) {
  return __builtin_amdgcn_rcpf(1.0f + __expf(-x));
}
__device__ __forceinline__ float tanh_(float x) {
  x = fminf(15.f, fmaxf(-15.f, x));
  float e = __expf(2.f * x);
  return (e - 1.f) * __builtin_amdgcn_rcpf(e + 1.f);
}

// ---- converts --------------------------------------------------------------
__global__ void k_conv_x(const float4* __restrict__ src,
                         ushort4* __restrict__ dst, long n4) {
  long i = blockIdx.x * (long)blockDim.x + threadIdx.x;
  long stride = (long)gridDim.x * blockDim.x;
  for (; i < n4; i += stride) {
    float4 v = src[i];
    ushort4 r;
    r.x = f2bf(v.x); r.y = f2bf(v.y); r.z = f2bf(v.z); r.w = f2bf(v.w);
    dst[i] = r;
  }
}
__global__ void k_conv_w(const float4* __restrict__ w0,
                         const float4* __restrict__ w1,
                         const float4* __restrict__ w2,
                         const float4* __restrict__ w3,
                         ushort4* __restrict__ dst) {
  const long per4 = (long)512 * 1024 / 4;
  long i = blockIdx.x * (long)blockDim.x + threadIdx.x;
  long stride = (long)gridDim.x * blockDim.x;
  for (; i < 4 * per4; i += stride) {
    long seg = i / per4, off2 = i - seg * per4;
    const float4* s = (seg == 0) ? w0 : (seg == 1) ? w1 : (seg == 2) ? w2 : w3;
    float4 v = s[off2];
    ushort4 r;
    r.x = f2bf(v.x); r.y = f2bf(v.y); r.z = f2bf(v.z); r.w = f2bf(v.w);
    dst[i] = r;
  }
}

#define BM 128
#define BN 128
#define BK 32

// ---- plain bf16 GEMM (FxAll only) ------------------------------------------
__global__ __launch_bounds__(256)
void k_gemm_bt(const uint16_t* __restrict__ A, int lda,
               const uint16_t* __restrict__ B, int ldb,
               float* __restrict__ C, int ldc, int K) {
  __shared__ uint16_t As[BM * BK];
  __shared__ uint16_t Bs[BN * BK];
  const int tid = threadIdx.x, lane = tid & 63, wave = tid >> 6;
  const int lrow = lane & 15, quad = lane >> 4;
  const int wm = (wave >> 1) * 64, wn = (wave & 1) * 64;
  const long tm = blockIdx.x, tn = blockIdx.y;
  f32x4 acc[4][4] = {};
  const int srow = lane >> 2, scol = (lane & 3) * 8;
  for (int k0 = 0; k0 < K; k0 += BK) {
#pragma unroll
    for (int i = 0; i < 2; ++i) {
      int row = i * 64 + wave * 16 + srow;
      const uint16_t* gp = A + (tm * BM + row) * (long)lda + k0 + scol;
      __builtin_amdgcn_global_load_lds((gbl_void_t*)(uintptr_t)gp,
          (lds_void_t*)&As[i * 2048 + wave * 512], 16, 0, 0);
    }
#pragma unroll
    for (int i = 0; i < 2; ++i) {
      int row = i * 64 + wave * 16 + srow;
      const uint16_t* gp = B + (tn * BN + row) * (long)ldb + k0 + scol;
      __builtin_amdgcn_global_load_lds((gbl_void_t*)(uintptr_t)gp,
          (lds_void_t*)&Bs[i * 2048 + wave * 512], 16, 0, 0);
    }
    __syncthreads();
    bf16x8 a[4], b[4];
#pragma unroll
    for (int f = 0; f < 4; ++f)
      a[f] = *(const bf16x8*)&As[(wm + f * 16 + lrow) * BK + quad * 8];
#pragma unroll
    for (int f = 0; f < 4; ++f)
      b[f] = *(const bf16x8*)&Bs[(wn + f * 16 + lrow) * BK + quad * 8];
#pragma unroll
    for (int fm = 0; fm < 4; ++fm)
#pragma unroll
      for (int fn = 0; fn < 4; ++fn)
        acc[fm][fn] = __builtin_amdgcn_mfma_f32_16x16x32_bf16(
            a[fm], b[fn], acc[fm][fn], 0, 0, 0);
    __syncthreads();
  }
#pragma unroll
  for (int fm = 0; fm < 4; ++fm)
#pragma unroll
    for (int fn = 0; fn < 4; ++fn) {
      long col  = tn * BN + wn + fn * 16 + lrow;
      long row0 = tm * BM + wm + fm * 16 + quad * 4;
#pragma unroll
      for (int r = 0; r < 4; ++r)
        C[(row0 + r) * (long)ldc + col] = acc[fm][fn][r];
    }
}

// ---- fused level kernel ----------------------------------------------------
// 1-D grid of nTm*8 blocks; XCD swizzle: x=b&7 (XCD), contiguous tm range per
// XCD, tn fastest. BK=64 as two 32-wide panels; one barrier pair per 64 K.
template <bool HAS_F>
__global__ __launch_bounds__(256, 3)
void k_level(const uint16_t* __restrict__ A, int lda, int K,
             const uint16_t* __restrict__ Wg,
             const float* __restrict__ bi, const float* __restrict__ bo,
             const float* __restrict__ bu,
             const float* __restrict__ Fpart,
             uint16_t* __restrict__ Cbf,
             const uint16_t* __restrict__ Xnext,
             uint16_t* __restrict__ xh_next) {
  __shared__ uint16_t As[2][128 * 32];      // 16 KB
  __shared__ uint16_t Bs[2][3 * 64 * 32];   // 24 KB
  const int tid = threadIdx.x, lane = tid & 63, wave = tid >> 6;
  const int lrow = lane & 15, quad = lane >> 4;
  const int wm = (wave >> 1) * 64, wn = (wave & 1) * 32;

  long tm, tn;
  {
    const int nTm = (int)(gridDim.x >> 3);
    int b = blockIdx.x;
    if ((nTm & 7) == 0) {           // XCD swizzle (dispatch round-robin mod 8)
      int x = b & 7, j = b >> 3, per = nTm >> 3;
      tn = j & 7; tm = (long)x * per + (j >> 3);
    } else { tm = b >> 3; tn = b & 7; }
  }

  f32x4 acc[3][4][2] = {};
  const int srow = lane >> 2, scol = (lane & 3) * 8;

  for (int k0 = 0; k0 < K; k0 += 64) {
#pragma unroll
    for (int h = 0; h < 2; ++h) {
      int kk = k0 + h * 32;
#pragma unroll
      for (int i = 0; i < 2; ++i) {
        int row = i * 64 + wave * 16 + srow;
        const uint16_t* gp = A + (tm * 128 + row) * (long)lda + kk + scol;
        __builtin_amdgcn_global_load_lds((gbl_void_t*)(uintptr_t)gp,
            (lds_void_t*)&As[h][i * 2048 + wave * 512], 16, 0, 0);
      }
#pragma unroll
      for (int g = 0; g < 3; ++g) {
        long grow = g * 512 + tn * 64 + wave * 16 + srow;
        const uint16_t* gp = Wg + grow * 1024 + kk + scol;
        __builtin_amdgcn_global_load_lds((gbl_void_t*)(uintptr_t)gp,
            (lds_void_t*)&Bs[h][g * 2048 + wave * 512], 16, 0, 0);
      }
    }
    __syncthreads();

#pragma unroll
    for (int h = 0; h < 2; ++h) {
      bf16x8 a[4];
#pragma unroll
      for (int f = 0; f < 4; ++f)
        a[f] = *(const bf16x8*)&As[h][(wm + f * 16 + lrow) * 32 + quad * 8];
#pragma unroll
      for (int g = 0; g < 3; ++g) {
        bf16x8 b0 = *(const bf16x8*)&Bs[h][g * 2048 + (wn + lrow) * 32 +
                                           quad * 8];
        bf16x8 b1 = *(const bf16x8*)&Bs[h][g * 2048 + (wn + 16 + lrow) * 32 +
                                           quad * 8];
#pragma unroll
        for (int fm = 0; fm < 4; ++fm) {
          acc[g][fm][0] = __builtin_amdgcn_mfma_f32_16x16x32_bf16(
              a[fm], b0, acc[g][fm][0], 0, 0, 0);
          acc[g][fm][1] = __builtin_amdgcn_mfma_f32_16x16x32_bf16(
              a[fm], b1, acc[g][fm][1], 0, 0, 0);
        }
      }
    }
    __syncthreads();
  }

  // epilogue — C/D layout: col = lane&15, row = quad*4 + r  [HW-verified]
#pragma unroll
  for (int fn = 0; fn < 2; ++fn) {
    long col = tn * 64 + wn + fn * 16 + lrow;
    float biv = bi[col], bov = bo[col], buv = bu[col];
#pragma unroll
    for (int fm = 0; fm < 4; ++fm) {
      long row0 = tm * 128 + wm + fm * 16 + quad * 4;
      long pg   = tm * 8 + (wm >> 4) + fm;
      float hs = 0.f;
#pragma unroll
      for (int r = 0; r < 4; ++r) {
        long row = row0 + r;
        float iv = sig_(acc[0][fm][fn][r] + biv);
        float ov = sig_(acc[1][fm][fn][r] + bov);
        float uv = tanh_(acc[2][fm][fn][r] + buv);
        float c  = iv * uv;
        if (HAS_F) c += Fpart[row * 512 + col];
        Cbf[row * 512 + col] = f2bf(c);
        hs += ov * tanh_(c);
      }
      hs += __shfl_xor(hs, 16, 64);
      hs += __shfl_xor(hs, 32, 64);
      if (quad == 0) {
        xh_next[pg * 1024 + col]       = Xnext[pg * 512 + col];
        xh_next[pg * 1024 + 512 + col] = f2bf(hs);
      }
    }
  }
}

// ---- fc GEMM + fused forget-combine (XCD-swizzled, BK=64 double panel) -----
__global__ __launch_bounds__(256, 3)
void k_fc_combine(const uint16_t* __restrict__ Cbf,
                  const uint16_t* __restrict__ Wfc, int ldb,
                  const float* __restrict__ Fx,
                  const float* __restrict__ bfb,
                  float* __restrict__ Fpart) {
  __shared__ uint16_t As[2][BM * BK];   // 16 KB
  __shared__ uint16_t Bs[2][BN * BK];   // 16 KB
  const int tid = threadIdx.x, lane = tid & 63, wave = tid >> 6;
  const int lrow = lane & 15, quad = lane >> 4;
  const int wm = (wave >> 1) * 64, wn = (wave & 1) * 64;
  long tm, tn;
  {
    const int nTm = (int)(gridDim.x >> 2);
    int b = blockIdx.x;
    if ((nTm & 7) == 0) {
      int x = b & 7, j = b >> 3, per = nTm >> 3;
      tn = j & 3; tm = (long)x * per + (j >> 2);
    } else { tm = b >> 2; tn = b & 3; }
  }
  const int lda = 512;
  f32x4 acc[4][4] = {};
  const int srow = lane >> 2, scol = (lane & 3) * 8;
  for (int k0 = 0; k0 < 512; k0 += 64) {
#pragma unroll
    for (int h = 0; h < 2; ++h) {
      int kk = k0 + h * 32;
#pragma unroll
      for (int i = 0; i < 2; ++i) {
        int row = i * 64 + wave * 16 + srow;
        const uint16_t* gp = Cbf + (tm * BM + row) * (long)lda + kk + scol;
        __builtin_amdgcn_global_load_lds((gbl_void_t*)(uintptr_t)gp,
            (lds_void_t*)&As[h][i * 2048 + wave * 512], 16, 0, 0);
      }
#pragma unroll
      for (int i = 0; i < 2; ++i) {
        int row = i * 64 + wave * 16 + srow;
        const uint16_t* gp = Wfc + (tn * BN + row) * (long)ldb + kk + scol;
        __builtin_amdgcn_global_load_lds((gbl_void_t*)(uintptr_t)gp,
            (lds_void_t*)&Bs[h][i * 2048 + wave * 512], 16, 0, 0);
      }
    }
    __syncthreads();
#pragma unroll
    for (int h = 0; h < 2; ++h) {
      bf16x8 a[4], b[4];
#pragma unroll
      for (int f = 0; f < 4; ++f)
        a[f] = *(const bf16x8*)&As[h][(wm + f * 16 + lrow) * BK + quad * 8];
#pragma unroll
      for (int f = 0; f < 4; ++f)
        b[f] = *(const bf16x8*)&Bs[h][(wn + f * 16 + lrow) * BK + quad * 8];
#pragma unroll
      for (int fm = 0; fm < 4; ++fm)
#pragma unroll
        for (int fn = 0; fn < 4; ++fn)
          acc[fm][fn] = __builtin_amdgcn_mfma_f32_16x16x32_bf16(
              a[fm], b[fn], acc[fm][fn], 0, 0, 0);
    }
    __syncthreads();
  }
#pragma unroll
  for (int fm = 0; fm < 4; ++fm) {
    long pg   = tm * 8 + (wm >> 4) + fm;
    long row0 = tm * BM + wm + fm * 16 + quad * 4;
#pragma unroll
    for (int fn = 0; fn < 4; ++fn) {
      long col = tn * BN + wn + fn * 16 + lrow;
      float fx = Fx[pg * 512 + col] + bfb[col];
      float t = 0.f;
#pragma unroll
      for (int r = 0; r < 4; ++r)
        t += sig_(fx + acc[fm][fn][r]) * bf2f(Cbf[(row0 + r) * 512 + col]);
      t += __shfl_xor(t, 16, 64);
      t += __shfl_xor(t, 32, 64);
      if (quad == 0) Fpart[pg * 512 + col] = t;
    }
  }
}

// ---- wave-per-dot kernels (tiny levels) ------------------------------------
__global__ void k_dot_bb(const uint16_t* __restrict__ A, int lda,
                         const uint16_t* __restrict__ B, int ldb,
                         float* __restrict__ C, int ldc,
                         int M, int N, int K) {
  int wid  = (int)((blockIdx.x * (long)blockDim.x + threadIdx.x) >> 6);
  int lane = threadIdx.x & 63;
  if (wid >= M * N) return;
  int m = wid / N, n = wid - m * N;
  const uint16_t* a = A + (long)m * lda;
  const uint16_t* b = B + (long)n * ldb;
  int per = K >> 6, k0 = lane * per;
  float s = 0.f;
  for (int j = 0; j < per; j += 4) {
    ushort4 av = *(const ushort4*)(a + k0 + j);
    ushort4 bv = *(const ushort4*)(b + k0 + j);
    s += bf2f(av.x) * bf2f(bv.x) + bf2f(av.y) * bf2f(bv.y)
       + bf2f(av.z) * bf2f(bv.z) + bf2f(av.w) * bf2f(bv.w);
  }
#pragma unroll
  for (int off = 32; off; off >>= 1) s += __shfl_xor(s, off, 64);
  if (lane == 0) C[(long)m * ldc + n] = s;
}
__global__ void k_dot_f32(const float* __restrict__ A, int lda,
                          const float* __restrict__ B, int ldb,
                          float* __restrict__ C, int ldc,
                          int M, int N, int K) {
  int wid  = (int)((blockIdx.x * (long)blockDim.x + threadIdx.x) >> 6);
  int lane = threadIdx.x & 63;
  if (wid >= M * N) return;
  int m = wid / N, n = wid - m * N;
  const float* a = A + (long)m * lda;
  const float* b = B + (long)n * ldb;
  int per = K >> 6, k0 = lane * per;
  float s = 0.f;
  for (int j = 0; j < per; j += 4) {
    float4 av = *(const float4*)(a + k0 + j);
    float4 bv = *(const float4*)(b + k0 + j);
    s += av.x * bv.x + av.y * bv.y + av.z * bv.z + av.w * bv.w;
  }
#pragma unroll
  for (int off = 32; off; off >>= 1) s += __shfl_xor(s, off, 64);
  if (lane == 0) C[(long)m * ldc + n] = s;
}

// ---- upper-level h_sum + pack xh -------------------------------------------
__global__ void k_hsum_xh4(const float* __restrict__ Hc,
                           const uint16_t* __restrict__ xd,
                           uint16_t* __restrict__ xh, int n) {
  long idx = blockIdx.x * (long)blockDim.x + threadIdx.x;
  if (idx >= (long)n * 128) return;
  long p = idx >> 7; int hq = (int)(idx & 127) << 2;
  const float* hp = Hc + (p << 4) * 512 + hq;
  float4 s = {0.f, 0.f, 0.f, 0.f};
#pragma unroll
  for (int b = 0; b < 16; ++b) {
    float4 v = *(const float4*)(hp + b * 512);
    s.x += v.x; s.y += v.y; s.z += v.z; s.w += v.w;
  }
  *(ushort4*)(xh + p * 1024 + hq) = *(const ushort4*)(xd + p * 512 + hq);
  ushort4 hw = {f2bf(s.x), f2bf(s.y), f2bf(s.z), f2bf(s.w)};
  *(ushort4*)(xh + p * 1024 + 512 + hq) = hw;
}

// ---- separate combine (d=0 exact path) -------------------------------------
__global__ void k_combine4(const float* __restrict__ Fc,
                           const float* __restrict__ Fx,
                           const float* __restrict__ bfb,
                           const float* __restrict__ Cc,
                           float* __restrict__ Fpart, int nParents) {
  long idx = blockIdx.x * (long)blockDim.x + threadIdx.x;
  if (idx >= (long)nParents * 128) return;
  long pl = idx >> 7; int hq = (int)(idx & 127) << 2;
  float4 fxv = *(const float4*)(Fx + pl * 512 + hq);
  float4 bfv = *(const float4*)(bfb + hq);
  float fx0 = fxv.x + bfv.x, fx1 = fxv.y + bfv.y;
  float fx2 = fxv.z + bfv.z, fx3 = fxv.w + bfv.w;
  float a0 = 0.f, a1 = 0.f, a2 = 0.f, a3 = 0.f;
#pragma unroll 4
  for (int b = 0; b < 16; ++b) {
    long cl = pl * 16 + b;
    float4 f = *(const float4*)(Fc + cl * 512 + hq);
    float4 c = *(const float4*)(Cc + cl * 512 + hq);
    a0 += sig_(fx0 + f.x) * c.x;
    a1 += sig_(fx1 + f.y) * c.y;
    a2 += sig_(fx2 + f.z) * c.z;
    a3 += sig_(fx3 + f.w) * c.w;
  }
  float4 r = {a0, a1, a2, a3};
  *(float4*)(Fpart + pl * 512 + hq) = r;
}

// ---- final for tiny levels -------------------------------------------------
__global__ void k_final4(const float* __restrict__ G,
                         const float* __restrict__ Fpart,
                         const float* __restrict__ bi,
                         const float* __restrict__ bo,
                         const float* __restrict__ bu,
                         float* __restrict__ H, float* __restrict__ Cv,
                         uint16_t* __restrict__ Cbf, int n) {
  long idx = blockIdx.x * (long)blockDim.x + threadIdx.x;
  if (idx >= (long)n * 128) return;
  long p = idx >> 7; int hq = (int)(idx & 127) << 2;
  const float* g = G + p * 1536;
  float4 gi = *(const float4*)(g + hq);
  float4 go = *(const float4*)(g + 512 + hq);
  float4 gu = *(const float4*)(g + 1024 + hq);
  float4 b_i = *(const float4*)(bi + hq);
  float4 b_o = *(const float4*)(bo + hq);
  float4 b_u = *(const float4*)(bu + hq);
  float4 fp = *(const float4*)(Fpart + p * 512 + hq);
  const float* gip = &gi.x; const float* gop = &go.x; const float* gup = &gu.x;
  const float* bip = &b_i.x; const float* bop = &b_o.x; const float* bup = &b_u.x;
  const float* fpp = &fp.x;
  float4 hv, cv;
  float* hvp = &hv.x; float* cvp = &cv.x;
  ushort4 cw; unsigned short* cwp = &cw.x;
#pragma unroll
  for (int j = 0; j < 4; ++j) {
    float iv = sig_(gip[j] + bip[j]);
    float ov = sig_(gop[j] + bop[j]);
    float uv = tanh_(gup[j] + bup[j]);
    float c  = iv * uv + fpp[j];
    cvp[j] = c;
    cwp[j] = f2bf(c);
    hvp[j] = ov * tanh_(c);
  }
  *(float4*)(H  + p * 512 + hq) = hv;
  *(float4*)(Cv + p * 512 + hq) = cv;
  *(ushort4*)(Cbf + p * 512 + hq) = cw;
}

// ---------------------------------------------------------------------------
extern "C" void kernel_launch(void* const* d_in, const int* in_sizes, int n_in,
                              void* d_out, int out_size, void* d_ws, size_t ws_size,
                              hipStream_t stream) {
  const float* x    = (const float*)d_in[0];
  const float* wi_w = (const float*)d_in[1];
  const float* wi_b = (const float*)d_in[2];
  const float* wf_w = (const float*)d_in[3];
  const float* wf_b = (const float*)d_in[4];
  const float* wo_w = (const float*)d_in[5];
  const float* wo_b = (const float*)d_in[6];
  const float* wu_w = (const float*)d_in[7];
  const float* wu_b = (const float*)d_in[8];
  (void)in_sizes; (void)n_in; (void)out_size; (void)ws_size;

  static const long offs[5] = {0, 1, 17, 273, 4369};
  const long NTOT = 69905;

  // ---- workspace (~175 MB of ~573 MB) ----
  char* ws = (char*)d_ws;
  size_t off = 0;
  auto alloc = [&](size_t bytes) -> void* {
    void* p = ws + off;
    off += (bytes + 255) & ~(size_t)255;
    return p;
  };
  uint16_t* Xbf   = (uint16_t*)alloc(NTOT * 512 * 2);
  uint16_t* Wgw   = (uint16_t*)alloc((size_t)2048 * 1024 * 2);
  uint16_t* Wg    = Wgw;
  uint16_t* Wf    = Wgw + (size_t)1536 * 1024;
  float*    FxAll = (float*)alloc((size_t)4480 * 512 * 4);
  uint16_t* Cbf   = (uint16_t*)alloc((size_t)65536 * 512 * 2);
  uint16_t* CbfU  = (uint16_t*)alloc((size_t)4096 * 512 * 2);
  uint16_t* CbfU2 = (uint16_t*)alloc((size_t)256 * 512 * 2);
  uint16_t* xhA   = (uint16_t*)alloc((size_t)4096 * 1024 * 2);
  uint16_t* xhB   = (uint16_t*)alloc((size_t)256 * 1024 * 2);
  uint16_t* xhC   = (uint16_t*)alloc((size_t)16 * 1024 * 2);
  float*    Fpart = (float*)alloc((size_t)4096 * 512 * 4);
  float*    Gf    = (float*)alloc((size_t)16 * 1536 * 4);
  float*    Fc    = (float*)alloc((size_t)16 * 512 * 4);
  float*    HupA  = (float*)alloc((size_t)16 * 512 * 4);
  float*    CupA  = (float*)alloc((size_t)16 * 512 * 4);

  auto blks = [](long n) { return (int)((n + 255) / 256); };

  // ---- converts ----
  {
    long n4 = NTOT * 512 / 4;
    k_conv_x<<<8192, 256, 0, stream>>>((const float4*)x, (ushort4*)Xbf, n4);
    k_conv_w<<<2048, 256, 0, stream>>>((const float4*)wi_w, (const float4*)wo_w,
                                       (const float4*)wu_w, (const float4*)wf_w,
                                       (ushort4*)Wgw);
  }

  // ---- Fx for all upper levels (node ids 0..4368, pad to 4480) ----
  {
    dim3 grid(35, 4);
    k_gemm_bt<<<grid, 256, 0, stream>>>(Xbf, 512, Wf, 1024, FxAll, 512, 512);
  }

  // ---- leaf level (M=65536, K=512): nTm=512, 1-D swizzled grid ----
  k_level<false><<<4096, 256, 0, stream>>>(
      Xbf + offs[4] * 512, 512, 512, Wg, wi_b, wo_b, wu_b, nullptr,
      Cbf, Xbf + offs[3] * 512, xhA);
  k_fc_combine<<<2048, 256, 0, stream>>>(Cbf, Wf + 512, 1024,
                                         FxAll + offs[3] * 512, wf_b, Fpart);

  // ---- level 3 (M=4096, K=1024): nTm=32 ----
  k_level<true><<<256, 256, 0, stream>>>(
      xhA, 1024, 1024, Wg, wi_b, wo_b, wu_b, Fpart,
      CbfU, Xbf + offs[2] * 512, xhB);
  k_fc_combine<<<128, 256, 0, stream>>>(CbfU, Wf + 512, 1024,
                                        FxAll + offs[2] * 512, wf_b, Fpart);

  // ---- level 2 (M=256, K=1024): nTm=2 (plain mapping) ----
  k_level<true><<<16, 256, 0, stream>>>(
      xhB, 1024, 1024, Wg, wi_b, wo_b, wu_b, Fpart,
      CbfU2, Xbf + offs[1] * 512, xhC);
  k_fc_combine<<<8, 256, 0, stream>>>(CbfU2, Wf + 512, 1024,
                                      FxAll + offs[1] * 512, wf_b, Fpart);

  // ---- level 1 (n=16) ----
  {
    long waves = 16L * 1536;
    k_dot_bb<<<(int)((waves * 64 + 255) / 256), 256, 0, stream>>>(
        xhC, 1024, Wg, 1024, Gf, 1536, 16, 1536, 1024);
    k_final4<<<blks(16L * 128), 256, 0, stream>>>(
        Gf, Fpart, wi_b, wo_b, wu_b, HupA, CupA, CbfU2, 16);
  }

  // ---- level 0 (root, exact fp32 fc path) ----
  k_hsum_xh4<<<1, 256, 0, stream>>>(HupA, Xbf + offs[0] * 512, xhC, 1);
  {
    long waves = 1536;
    k_dot_bb<<<(int)((waves * 64 + 255) / 256), 256, 0, stream>>>(
        xhC, 1024, Wg, 1024, Gf, 1536, 1, 1536, 1024);
  }
  {
    long waves = 16L * 512;
    k_dot_f32<<<(int)((waves * 64 + 255) / 256), 256, 0, stream>>>(
        CupA, 512, wf_w + 512, 1024, Fc, 512, 16, 512, 512);
  }
  k_combine4<<<1, 256, 0, stream>>>(Fc, FxAll, wf_b, CupA, Fpart, 1);
  k_final4<<<1, 256, 0, stream>>>(
      Gf, Fpart, wi_b, wo_b, wu_b,
      (float*)d_out, (float*)d_out + 512, CbfU2, 1);
}